// Round 1
// baseline (473.692 us; speedup 1.0000x reference)
//
#include <hip/hip_runtime.h>
#include <hip/hip_bf16.h>

typedef __bf16 bf16_t;
typedef __attribute__((ext_vector_type(8))) __bf16 bf16x8;
typedef __attribute__((ext_vector_type(4))) float f32x4;

__device__ __forceinline__ void gld_lds16(const void* g, void* l) {
  __builtin_amdgcn_global_load_lds((const __attribute__((address_space(1))) void*)g,
                                   (__attribute__((address_space(3))) void*)l, 16, 0, 0);
}

// ---------------------------------------------------------------- cast+concat
// Xcat[8192][3072] bf16 = [words | position | conscious]
__global__ __launch_bounds__(256) void cast_concat(
    const float* __restrict__ w, const float* __restrict__ p,
    const float* __restrict__ c, bf16_t* __restrict__ X)
{
  unsigned idx = blockIdx.x * 256u + threadIdx.x;   // one 4-float chunk
  unsigned src = idx >> 21;                         // 8192*256 = 2^21 chunks/source
  unsigned rem = idx & ((1u << 21) - 1);
  unsigned row = rem >> 8;
  unsigned k4  = (rem & 255u) * 4u;
  const float* s = (src == 0) ? w : (src == 1) ? p : c;
  f32x4 v = *(const f32x4*)(s + (size_t)row * 1024 + k4);
  ushort4 u;
  u.x = __builtin_bit_cast(unsigned short, (bf16_t)v[0]);
  u.y = __builtin_bit_cast(unsigned short, (bf16_t)v[1]);
  u.z = __builtin_bit_cast(unsigned short, (bf16_t)v[2]);
  u.w = __builtin_bit_cast(unsigned short, (bf16_t)v[3]);
  *(ushort4*)(X + (size_t)row * 3072 + src * 1024 + k4) = u;
}

// ---------------------------------------------------------------- W transpose
// dst[n][k_off + k] = (bf16) src[k][n]   (src is [1024][1024] f32 row-major)
__global__ __launch_bounds__(256) void transpose_w(
    const float* __restrict__ src, bf16_t* __restrict__ dst,
    int dst_stride, int k_off)
{
  __shared__ float t[32][33];
  int bx = blockIdx.x, by = blockIdx.y;
  int x = bx * 32 + threadIdx.x;
  int y0 = by * 32;
  for (int i = threadIdx.y; i < 32; i += 8)
    t[i][threadIdx.x] = src[(size_t)(y0 + i) * 1024 + x];
  __syncthreads();
  int n0 = bx * 32;
  for (int i = threadIdx.y; i < 32; i += 8)
    dst[(size_t)(n0 + i) * dst_stride + k_off + y0 + threadIdx.x] =
        (bf16_t)t[threadIdx.x][i];
}

// ---------------------------------------------------------------- GEMM (B^T)
// C[M=8192, N=1024] = A[M,K] * Bt[N,K]^T ; 128x128 tile, BK=32, 4 waves.
// EPI 0: bf16 out to [B,H,N,D] with scale.  EPI 1: bf16 out to V^T [B,H,D,N].
// EPI 2: f32 out row-major + bias.
template<int EPI>
__global__ __launch_bounds__(256, 2) void gemm_bt(
    const bf16_t* __restrict__ A, int lda,
    const bf16_t* __restrict__ Bt, int K,
    void* __restrict__ Cout, const float* __restrict__ bias, float scale)
{
  __shared__ bf16_t As[128 * 32];
  __shared__ bf16_t Bs[128 * 32];
  const int tid  = threadIdx.x;
  const int wave = tid >> 6, lane = tid & 63;
  const int m0 = blockIdx.y * 128, n0 = blockIdx.x * 128;
  const int wr = (wave >> 1) * 64, wc = (wave & 1) * 64;
  const int lrow = lane & 15, lch = lane >> 4;

  f32x4 acc[4][4] = {};

  for (int k0 = 0; k0 < K; k0 += 32) {
    __syncthreads();
#pragma unroll
    for (int t = 0; t < 2; ++t) {
      int cc = t * 256 + tid;
      int row = cc >> 2, pp = cc & 3;
      int kswz = (pp ^ (row & 3)) * 8;          // pre-swizzled global source (rule #21)
      gld_lds16(A  + (size_t)(m0 + row) * lda + k0 + kswz, &As[cc * 8]);
      gld_lds16(Bt + (size_t)(n0 + row) * K   + k0 + kswz, &Bs[cc * 8]);
    }
    __syncthreads();
    bf16x8 a[4], b[4];
#pragma unroll
    for (int i = 0; i < 4; ++i) {
      int r = wr + i * 16 + lrow;
      a[i] = *(const bf16x8*)&As[r * 32 + ((lch ^ (r & 3)) * 8)];
    }
#pragma unroll
    for (int i = 0; i < 4; ++i) {
      int r = wc + i * 16 + lrow;
      b[i] = *(const bf16x8*)&Bs[r * 32 + ((lch ^ (r & 3)) * 8)];
    }
#pragma unroll
    for (int i = 0; i < 4; ++i)
#pragma unroll
      for (int j = 0; j < 4; ++j)
        acc[i][j] = __builtin_amdgcn_mfma_f32_16x16x32_bf16(a[i], b[j], acc[i][j], 0, 0, 0);
  }

  const int g = lane >> 4, cl = lane & 15;
  if (EPI == 0) {
    bf16_t* Qo = (bf16_t*)Cout;
#pragma unroll
    for (int i = 0; i < 4; ++i) {
      int m_base = m0 + wr + i * 16 + g * 4;
      int bb = m_base >> 11, nn = m_base & 2047;
#pragma unroll
      for (int j = 0; j < 4; ++j) {
        int col = n0 + wc + j * 16 + cl;
        int h = col >> 6, d = col & 63;
        size_t base = ((size_t)(bb * 16 + h) * 2048 + nn) * 64 + d;
#pragma unroll
        for (int r = 0; r < 4; ++r)
          Qo[base + (size_t)r * 64] = (bf16_t)(acc[i][j][r] * scale);
      }
    }
  } else if (EPI == 1) {
    bf16_t* Vo = (bf16_t*)Cout;
#pragma unroll
    for (int i = 0; i < 4; ++i) {
      int m_base = m0 + wr + i * 16 + g * 4;
      int bb = m_base >> 11, nn = m_base & 2047;
#pragma unroll
      for (int j = 0; j < 4; ++j) {
        int col = n0 + wc + j * 16 + cl;
        int h = col >> 6, d = col & 63;
        ushort4 u;
        u.x = __builtin_bit_cast(unsigned short, (bf16_t)acc[i][j][0]);
        u.y = __builtin_bit_cast(unsigned short, (bf16_t)acc[i][j][1]);
        u.z = __builtin_bit_cast(unsigned short, (bf16_t)acc[i][j][2]);
        u.w = __builtin_bit_cast(unsigned short, (bf16_t)acc[i][j][3]);
        *(ushort4*)(Vo + ((size_t)(bb * 16 + h) * 64 + d) * 2048 + nn) = u;
      }
    }
  } else {
    float* Co = (float*)Cout;
#pragma unroll
    for (int i = 0; i < 4; ++i) {
      int m_base = m0 + wr + i * 16 + g * 4;
#pragma unroll
      for (int j = 0; j < 4; ++j) {
        int col = n0 + wc + j * 16 + cl;
        float bv = bias[col];
#pragma unroll
        for (int r = 0; r < 4; ++r)
          Co[(size_t)(m_base + r) * 1024 + col] = acc[i][j][r] + bv;
      }
    }
  }
}

// ---------------------------------------------------------------- attention
// grid (16 qtiles, 64 b*h), 256 threads, QBLK=128 (32 rows/wave), KVBLK=64.
__global__ __launch_bounds__(256, 2) void attn_kernel(
    const bf16_t* __restrict__ Q, const bf16_t* __restrict__ Kb,
    const bf16_t* __restrict__ Vt, bf16_t* __restrict__ O)
{
  __shared__ bf16_t Ks[64 * 64];
  __shared__ bf16_t Vs[64 * 64];
  __shared__ bf16_t Plds[4][32][72];

  const int qt = blockIdx.x;
  const int bh = blockIdx.y;
  const int bb = bh >> 4, h = bh & 15;
  const int tid = threadIdx.x, wave = tid >> 6, lane = tid & 63;
  const int lrow = lane & 15, lch = lane >> 4;
  const int g = lch, cl = lrow;

  const bf16_t* Qb    = Q  + ((size_t)bh * 2048 + qt * 128) * 64;
  const bf16_t* Kbase = Kb + (size_t)bh * 2048 * 64;
  const bf16_t* Vbase = Vt + (size_t)bh * 64 * 2048;

  // Q fragments in registers (scale already folded into Q buffer)
  bf16x8 qf[2][2];
#pragma unroll
  for (int mf = 0; mf < 2; ++mf)
#pragma unroll
    for (int kf = 0; kf < 2; ++kf)
      qf[mf][kf] = *(const bf16x8*)(Qb + (size_t)(wave * 32 + mf * 16 + lrow) * 64 + kf * 32 + lch * 8);

  f32x4 acc[2][4] = {};
  float mrow[2][4], lsum[2][4];
#pragma unroll
  for (int mf = 0; mf < 2; ++mf)
#pragma unroll
    for (int r = 0; r < 4; ++r) { mrow[mf][r] = -3.0e38f; lsum[mf][r] = 0.f; }

  for (int kv0 = 0; kv0 < 2048; kv0 += 64) {
    __syncthreads();
#pragma unroll
    for (int t = 0; t < 2; ++t) {
      int cc = t * 256 + tid;
      int row = cc >> 3, pp = cc & 7;
      int swz = (pp ^ (row & 7)) * 8;          // both-sides XOR swizzle (G4 / rule #21)
      gld_lds16(Kbase + (size_t)(kv0 + row) * 64 + swz,   &Ks[cc * 8]);
      gld_lds16(Vbase + (size_t)row * 2048 + kv0 + swz,   &Vs[cc * 8]);
    }
    __syncthreads();

    // S = Q K^T   (D layout: row = q = g*4+r (+16mf), col = kv = nf*16+cl)
    f32x4 s[2][4] = {};
#pragma unroll
    for (int nf = 0; nf < 4; ++nf) {
      int r = nf * 16 + lrow;
#pragma unroll
      for (int kf = 0; kf < 2; ++kf) {
        int q = kf * 4 + lch;
        bf16x8 kfr = *(const bf16x8*)&Ks[r * 64 + ((q ^ (r & 7)) * 8)];
#pragma unroll
        for (int mf = 0; mf < 2; ++mf)
          s[mf][nf] = __builtin_amdgcn_mfma_f32_16x16x32_bf16(qf[mf][kf], kfr, s[mf][nf], 0, 0, 0);
      }
    }

    // online softmax, wave-parallel (16-lane-group shuffle reduce)
#pragma unroll
    for (int mf = 0; mf < 2; ++mf) {
#pragma unroll
      for (int r = 0; r < 4; ++r) {
        float mx = fmaxf(fmaxf(s[mf][0][r], s[mf][1][r]), fmaxf(s[mf][2][r], s[mf][3][r]));
        mx = fmaxf(mx, __shfl_xor(mx, 1));
        mx = fmaxf(mx, __shfl_xor(mx, 2));
        mx = fmaxf(mx, __shfl_xor(mx, 4));
        mx = fmaxf(mx, __shfl_xor(mx, 8));
        float mnew = fmaxf(mrow[mf][r], mx);
        float corr = __expf(mrow[mf][r] - mnew);
        mrow[mf][r] = mnew;
        float sm = 0.f;
#pragma unroll
        for (int nf = 0; nf < 4; ++nf) {
          float pv = __expf(s[mf][nf][r] - mnew);
          s[mf][nf][r] = pv;
          sm += pv;
        }
        sm += __shfl_xor(sm, 1);
        sm += __shfl_xor(sm, 2);
        sm += __shfl_xor(sm, 4);
        sm += __shfl_xor(sm, 8);
        lsum[mf][r] = lsum[mf][r] * corr + sm;
#pragma unroll
        for (int df = 0; df < 4; ++df) acc[mf][df][r] *= corr;
      }
    }

    // P -> per-wave LDS (padded), then PV
#pragma unroll
    for (int mf = 0; mf < 2; ++mf)
#pragma unroll
      for (int nf = 0; nf < 4; ++nf)
#pragma unroll
        for (int r = 0; r < 4; ++r)
          Plds[wave][mf * 16 + g * 4 + r][nf * 16 + cl] = (bf16_t)s[mf][nf][r];

#pragma unroll
    for (int kf = 0; kf < 2; ++kf) {
      bf16x8 ap[2];
#pragma unroll
      for (int mf = 0; mf < 2; ++mf)
        ap[mf] = *(const bf16x8*)&Plds[wave][mf * 16 + lrow][kf * 32 + lch * 8];
#pragma unroll
      for (int df = 0; df < 4; ++df) {
        int r = df * 16 + lrow;
        int q = kf * 4 + lch;
        bf16x8 bv = *(const bf16x8*)&Vs[r * 64 + ((q ^ (r & 7)) * 8)];
#pragma unroll
        for (int mf = 0; mf < 2; ++mf)
          acc[mf][df] = __builtin_amdgcn_mfma_f32_16x16x32_bf16(ap[mf], bv, acc[mf][df], 0, 0, 0);
      }
    }
  }

  // normalize + write O as [B, N, H*D] bf16
#pragma unroll
  for (int mf = 0; mf < 2; ++mf) {
#pragma unroll
    for (int r = 0; r < 4; ++r) {
      float inv = 1.0f / lsum[mf][r];
      int nn = qt * 128 + wave * 32 + mf * 16 + g * 4 + r;
      size_t base = ((size_t)bb * 2048 + nn) * 1024 + h * 64;
#pragma unroll
      for (int df = 0; df < 4; ++df)
        O[base + df * 16 + cl] = (bf16_t)(acc[mf][df][r] * inv);
    }
  }
}

// ---------------------------------------------------------------- launch
extern "C" void kernel_launch(void* const* d_in, const int* in_sizes, int n_in,
                              void* d_out, int out_size, void* d_ws, size_t ws_size,
                              hipStream_t stream) {
  const float* words     = (const float*)d_in[0];
  const float* position  = (const float*)d_in[1];
  const float* conscious = (const float*)d_in[2];
  const float* w_wq  = (const float*)d_in[3];
  const float* w_wk  = (const float*)d_in[4];
  const float* w_wv  = (const float*)d_in[5];
  const float* w_pq  = (const float*)d_in[6];
  const float* w_pk  = (const float*)d_in[7];
  const float* w_cq  = (const float*)d_in[8];
  const float* w_ck  = (const float*)d_in[9];
  const float* w_out = (const float*)d_in[10];
  const float* b_out = (const float*)d_in[11];

  char* ws = (char*)d_ws;
  bf16_t* Xcat = (bf16_t*)(ws);                 // 8192*3072*2 = 48 MiB
  bf16_t* Wqt  = (bf16_t*)(ws + 50331648);      // 6 MiB
  bf16_t* Wkt  = (bf16_t*)(ws + 56623104);      // 6 MiB
  bf16_t* Wvt  = (bf16_t*)(ws + 62914560);      // 2 MiB
  bf16_t* Wot  = (bf16_t*)(ws + 65011712);      // 2 MiB
  bf16_t* Qb   = (bf16_t*)(ws + 67108864);      // 16 MiB [B,H,N,D]
  bf16_t* Kbf  = (bf16_t*)(ws + 83886080);      // 16 MiB [B,H,N,D]
  bf16_t* Vtb  = (bf16_t*)(ws + 100663296);     // 16 MiB [B,H,D,N]
  bf16_t* Ob   = (bf16_t*)(ws + 117440512);     // 16 MiB [B,N,H*D]

  cast_concat<<<24576, 256, 0, stream>>>(words, position, conscious, Xcat);

  dim3 tb(32, 8), tg(32, 32);
  transpose_w<<<tg, tb, 0, stream>>>(w_wq,  Wqt, 3072, 0);
  transpose_w<<<tg, tb, 0, stream>>>(w_pq,  Wqt, 3072, 1024);
  transpose_w<<<tg, tb, 0, stream>>>(w_cq,  Wqt, 3072, 2048);
  transpose_w<<<tg, tb, 0, stream>>>(w_wk,  Wkt, 3072, 0);
  transpose_w<<<tg, tb, 0, stream>>>(w_pk,  Wkt, 3072, 1024);
  transpose_w<<<tg, tb, 0, stream>>>(w_ck,  Wkt, 3072, 2048);
  transpose_w<<<tg, tb, 0, stream>>>(w_wv,  Wvt, 1024, 0);
  transpose_w<<<tg, tb, 0, stream>>>(w_out, Wot, 1024, 0);

  dim3 gg(8, 64);  // N/128, M/128
  gemm_bt<0><<<gg, 256, 0, stream>>>(Xcat, 3072, Wqt, 3072, Qb,  nullptr, 0.125f);
  gemm_bt<0><<<gg, 256, 0, stream>>>(Xcat, 3072, Wkt, 3072, Kbf, nullptr, 1.0f);
  gemm_bt<1><<<gg, 256, 0, stream>>>(Xcat, 3072, Wvt, 1024, Vtb, nullptr, 1.0f);

  attn_kernel<<<dim3(16, 64), 256, 0, stream>>>(Qb, Kbf, Vtb, Ob);

  gemm_bt<2><<<gg, 256, 0, stream>>>(Ob, 1024, Wot, 1024, (float*)d_out, b_out, 1.0f);
}

// Round 2
// 372.667 us; speedup vs baseline: 1.2711x; 1.2711x over previous
//
#include <hip/hip_runtime.h>
#include <hip/hip_bf16.h>

typedef __bf16 bf16_t;
typedef __attribute__((ext_vector_type(8))) __bf16 bf16x8;
typedef __attribute__((ext_vector_type(4))) float f32x4;

__device__ __forceinline__ void gld_lds16(const void* g, void* l) {
  __builtin_amdgcn_global_load_lds((const __attribute__((address_space(1))) void*)g,
                                   (__attribute__((address_space(3))) void*)l, 16, 0, 0);
}

// ---------------------------------------------------------------- cast+concat
// Xcat[8192][3072] bf16 = [words | position | conscious]
__global__ __launch_bounds__(256) void cast_concat(
    const float* __restrict__ w, const float* __restrict__ p,
    const float* __restrict__ c, bf16_t* __restrict__ X)
{
  unsigned idx = blockIdx.x * 256u + threadIdx.x;   // one 4-float chunk
  unsigned src = idx >> 21;                         // 8192*256 = 2^21 chunks/source
  unsigned rem = idx & ((1u << 21) - 1);
  unsigned row = rem >> 8;
  unsigned k4  = (rem & 255u) * 4u;
  const float* s = (src == 0) ? w : (src == 1) ? p : c;
  f32x4 v = *(const f32x4*)(s + (size_t)row * 1024 + k4);
  ushort4 u;
  u.x = __builtin_bit_cast(unsigned short, (bf16_t)v[0]);
  u.y = __builtin_bit_cast(unsigned short, (bf16_t)v[1]);
  u.z = __builtin_bit_cast(unsigned short, (bf16_t)v[2]);
  u.w = __builtin_bit_cast(unsigned short, (bf16_t)v[3]);
  *(ushort4*)(X + (size_t)row * 3072 + src * 1024 + k4) = u;
}

// ---------------------------------------------------------------- W transpose
__global__ __launch_bounds__(256) void transpose_w(
    const float* __restrict__ src, bf16_t* __restrict__ dst,
    int dst_stride, int k_off)
{
  __shared__ float t[32][33];
  int bx = blockIdx.x, by = blockIdx.y;
  int x = bx * 32 + threadIdx.x;
  int y0 = by * 32;
  for (int i = threadIdx.y; i < 32; i += 8)
    t[i][threadIdx.x] = src[(size_t)(y0 + i) * 1024 + x];
  __syncthreads();
  int n0 = bx * 32;
  for (int i = threadIdx.y; i < 32; i += 8)
    dst[(size_t)(n0 + i) * dst_stride + k_off + y0 + threadIdx.x] =
        (bf16_t)t[threadIdx.x][i];
}

// ---------------------------------------------------------------- GEMM (B^T)
template<int EPI>
__global__ __launch_bounds__(256, 2) void gemm_bt(
    const bf16_t* __restrict__ A, int lda,
    const bf16_t* __restrict__ Bt, int K,
    void* __restrict__ Cout, const float* __restrict__ bias, float scale)
{
  __shared__ bf16_t As[128 * 32];
  __shared__ bf16_t Bs[128 * 32];
  const int tid  = threadIdx.x;
  const int wave = tid >> 6, lane = tid & 63;
  const int m0 = blockIdx.y * 128, n0 = blockIdx.x * 128;
  const int wr = (wave >> 1) * 64, wc = (wave & 1) * 64;
  const int lrow = lane & 15, lch = lane >> 4;

  f32x4 acc[4][4] = {};

  for (int k0 = 0; k0 < K; k0 += 32) {
    __syncthreads();
#pragma unroll
    for (int t = 0; t < 2; ++t) {
      int cc = t * 256 + tid;
      int row = cc >> 2, pp = cc & 3;
      int kswz = (pp ^ (row & 3)) * 8;
      gld_lds16(A  + (size_t)(m0 + row) * lda + k0 + kswz, &As[cc * 8]);
      gld_lds16(Bt + (size_t)(n0 + row) * K   + k0 + kswz, &Bs[cc * 8]);
    }
    __syncthreads();
    bf16x8 a[4], b[4];
#pragma unroll
    for (int i = 0; i < 4; ++i) {
      int r = wr + i * 16 + lrow;
      a[i] = *(const bf16x8*)&As[r * 32 + ((lch ^ (r & 3)) * 8)];
    }
#pragma unroll
    for (int i = 0; i < 4; ++i) {
      int r = wc + i * 16 + lrow;
      b[i] = *(const bf16x8*)&Bs[r * 32 + ((lch ^ (r & 3)) * 8)];
    }
#pragma unroll
    for (int i = 0; i < 4; ++i)
#pragma unroll
      for (int j = 0; j < 4; ++j)
        acc[i][j] = __builtin_amdgcn_mfma_f32_16x16x32_bf16(a[i], b[j], acc[i][j], 0, 0, 0);
  }

  const int g = lane >> 4, cl = lane & 15;
  if (EPI == 0) {
    bf16_t* Qo = (bf16_t*)Cout;
#pragma unroll
    for (int i = 0; i < 4; ++i) {
      int m_base = m0 + wr + i * 16 + g * 4;
      int bb = m_base >> 11, nn = m_base & 2047;
#pragma unroll
      for (int j = 0; j < 4; ++j) {
        int col = n0 + wc + j * 16 + cl;
        int h = col >> 6, d = col & 63;
        size_t base = ((size_t)(bb * 16 + h) * 2048 + nn) * 64 + d;
#pragma unroll
        for (int r = 0; r < 4; ++r)
          Qo[base + (size_t)r * 64] = (bf16_t)(acc[i][j][r] * scale);
      }
    }
  } else if (EPI == 1) {
    bf16_t* Vo = (bf16_t*)Cout;
#pragma unroll
    for (int i = 0; i < 4; ++i) {
      int m_base = m0 + wr + i * 16 + g * 4;
      int bb = m_base >> 11, nn = m_base & 2047;
#pragma unroll
      for (int j = 0; j < 4; ++j) {
        int col = n0 + wc + j * 16 + cl;
        int h = col >> 6, d = col & 63;
        ushort4 u;
        u.x = __builtin_bit_cast(unsigned short, (bf16_t)acc[i][j][0]);
        u.y = __builtin_bit_cast(unsigned short, (bf16_t)acc[i][j][1]);
        u.z = __builtin_bit_cast(unsigned short, (bf16_t)acc[i][j][2]);
        u.w = __builtin_bit_cast(unsigned short, (bf16_t)acc[i][j][3]);
        *(ushort4*)(Vo + ((size_t)(bb * 16 + h) * 64 + d) * 2048 + nn) = u;
      }
    }
  } else {
    float* Co = (float*)Cout;
#pragma unroll
    for (int i = 0; i < 4; ++i) {
      int m_base = m0 + wr + i * 16 + g * 4;
#pragma unroll
      for (int j = 0; j < 4; ++j) {
        int col = n0 + wc + j * 16 + cl;
        float bv = bias[col];
#pragma unroll
        for (int r = 0; r < 4; ++r)
          Co[(size_t)(m_base + r) * 1024 + col] = acc[i][j][r] + bv;
      }
    }
  }
}

// ---------------------------------------------------------------- attention v2
// Swapped-operand flash attention: S^T = mfma(K,Q) puts q = lane&15 so softmax
// state is lane-local; PV also swapped: acc = out^T with q = lane&15.
// Grid: 1024 1-D blocks, XCD-swizzled so each XCD covers 8 heads (KV fits L2).
__global__ __launch_bounds__(256, 2) void attn_kernel(
    const bf16_t* __restrict__ Q, const bf16_t* __restrict__ Kb,
    const bf16_t* __restrict__ Vt, bf16_t* __restrict__ O)
{
  __shared__ bf16_t Ks[64 * 64];
  __shared__ bf16_t Vs[64 * 64];
  __shared__ bf16_t Pw[4][32][72];   // per-wave P[q][kv], stride 72 (16B-aligned rows)

  // XCD swizzle: round-robin fid%8 -> contiguous 128-block chunk -> 8 heads/XCD
  const int fid = blockIdx.x;
  const int swz = (fid & 7) * 128 + (fid >> 3);
  const int bh = swz >> 4, qt = swz & 15;
  const int bb = bh >> 4, h = bh & 15;

  const int tid = threadIdx.x, wave = tid >> 6, lane = tid & 63;
  const int lrow = lane & 15, lch = lane >> 4;
  const int g = lch, cl = lrow;

  const bf16_t* Qb    = Q  + ((size_t)bh * 2048 + qt * 128) * 64;
  const bf16_t* Kbase = Kb + (size_t)bh * 2048 * 64;
  const bf16_t* Vbase = Vt + (size_t)bh * 64 * 2048;

  // Q fragments (log2e*scale folded into Q buffer)
  bf16x8 qf[2][2];
#pragma unroll
  for (int mf = 0; mf < 2; ++mf)
#pragma unroll
    for (int kf = 0; kf < 2; ++kf)
      qf[mf][kf] = *(const bf16x8*)(Qb + (size_t)(wave * 32 + mf * 16 + lrow) * 64 + kf * 32 + lch * 8);

  f32x4 acc[4][2] = {};          // acc[ddf][mf]: out^T, d = ddf*16+g*4+r, q = mf*16+cl
  float m_run[2] = {-1.0e30f, -1.0e30f};
  float l_run[2] = {0.f, 0.f};

  for (int kv0 = 0; kv0 < 2048; kv0 += 64) {
    __syncthreads();
#pragma unroll
    for (int t = 0; t < 2; ++t) {
      int cc = t * 256 + tid;
      int row = cc >> 3, pp = cc & 7;
      int swzk = (pp ^ (row & 7)) * 8;         // both-sides XOR swizzle
      gld_lds16(Kbase + (size_t)(kv0 + row) * 64 + swzk, &Ks[cc * 8]);
      gld_lds16(Vbase + (size_t)row * 2048 + kv0 + swzk, &Vs[cc * 8]);
    }
    __syncthreads();

    // S^T = K Q^T  (frags st[nf][mf]: kv = nf*16+g*4+r, q = mf*16+cl)
    f32x4 st[4][2] = {};
#pragma unroll
    for (int nf = 0; nf < 4; ++nf) {
      int r = nf * 16 + lrow;
#pragma unroll
      for (int kf = 0; kf < 2; ++kf) {
        int q = kf * 4 + lch;
        bf16x8 kfr = *(const bf16x8*)&Ks[r * 64 + ((q ^ (r & 7)) * 8)];
#pragma unroll
        for (int mf = 0; mf < 2; ++mf)
          st[nf][mf] = __builtin_amdgcn_mfma_f32_16x16x32_bf16(kfr, qf[mf][kf], st[nf][mf], 0, 0, 0);
      }
    }

    // online softmax (log2 domain), lane-local per q-column
#pragma unroll
    for (int mf = 0; mf < 2; ++mf) {
      float t0 = fmaxf(fmaxf(st[0][mf][0], st[0][mf][1]), fmaxf(st[0][mf][2], st[0][mf][3]));
      float t1 = fmaxf(fmaxf(st[1][mf][0], st[1][mf][1]), fmaxf(st[1][mf][2], st[1][mf][3]));
      float t2 = fmaxf(fmaxf(st[2][mf][0], st[2][mf][1]), fmaxf(st[2][mf][2], st[2][mf][3]));
      float t3 = fmaxf(fmaxf(st[3][mf][0], st[3][mf][1]), fmaxf(st[3][mf][2], st[3][mf][3]));
      float tmax = fmaxf(fmaxf(t0, t1), fmaxf(t2, t3));
      tmax = fmaxf(tmax, __shfl_xor(tmax, 16));
      tmax = fmaxf(tmax, __shfl_xor(tmax, 32));
      // defer-rescale (T13, THR=8 in log2 domain)
      if (!__all(tmax <= m_run[mf] + 8.0f)) {
        float mnew = fmaxf(m_run[mf], tmax);
        float corr = __builtin_amdgcn_exp2f(m_run[mf] - mnew);
        m_run[mf] = mnew;
        l_run[mf] *= corr;
#pragma unroll
        for (int ddf = 0; ddf < 4; ++ddf)
#pragma unroll
          for (int r = 0; r < 4; ++r) acc[ddf][mf][r] *= corr;
      }
      float mm = m_run[mf];
      float sm = 0.f;
#pragma unroll
      for (int nf = 0; nf < 4; ++nf) {
        f32x4 pv;
#pragma unroll
        for (int r = 0; r < 4; ++r) {
          pv[r] = __builtin_amdgcn_exp2f(st[nf][mf][r] - mm);
          st[nf][mf][r] = pv[r];
        }
        sm += (pv[0] + pv[1]) + (pv[2] + pv[3]);
        // pack 4 bf16 -> one 8B LDS write: P[q][kv], row q = mf*16+cl
        ushort4 u;
        u.x = __builtin_bit_cast(unsigned short, (bf16_t)pv[0]);
        u.y = __builtin_bit_cast(unsigned short, (bf16_t)pv[1]);
        u.z = __builtin_bit_cast(unsigned short, (bf16_t)pv[2]);
        u.w = __builtin_bit_cast(unsigned short, (bf16_t)pv[3]);
        *(ushort4*)&Pw[wave][mf * 16 + cl][nf * 16 + g * 4] = u;
      }
      sm += __shfl_xor(sm, 16);
      sm += __shfl_xor(sm, 32);
      l_run[mf] += sm;
    }

    // PV (swapped): acc[ddf][mf] += mfma(Vt_rows, P_rows)
#pragma unroll
    for (int kf = 0; kf < 2; ++kf) {
      bf16x8 pb[2];
#pragma unroll
      for (int mf = 0; mf < 2; ++mf)
        pb[mf] = *(const bf16x8*)&Pw[wave][mf * 16 + lrow][kf * 32 + lch * 8];
#pragma unroll
      for (int ddf = 0; ddf < 4; ++ddf) {
        int r = ddf * 16 + lrow;
        int q = kf * 4 + lch;
        bf16x8 va = *(const bf16x8*)&Vs[r * 64 + ((q ^ (r & 7)) * 8)];
#pragma unroll
        for (int mf = 0; mf < 2; ++mf)
          acc[ddf][mf] = __builtin_amdgcn_mfma_f32_16x16x32_bf16(va, pb[mf], acc[ddf][mf], 0, 0, 0);
      }
    }
  }

  // normalize + write O as [B, N, H*D] bf16 (packed 8B stores)
#pragma unroll
  for (int mf = 0; mf < 2; ++mf) {
    float inv = 1.0f / l_run[mf];
    int nn = qt * 128 + wave * 32 + mf * 16 + cl;
    size_t base = ((size_t)bb * 2048 + nn) * 1024 + h * 64;
#pragma unroll
    for (int ddf = 0; ddf < 4; ++ddf) {
      ushort4 u;
      u.x = __builtin_bit_cast(unsigned short, (bf16_t)(acc[ddf][mf][0] * inv));
      u.y = __builtin_bit_cast(unsigned short, (bf16_t)(acc[ddf][mf][1] * inv));
      u.z = __builtin_bit_cast(unsigned short, (bf16_t)(acc[ddf][mf][2] * inv));
      u.w = __builtin_bit_cast(unsigned short, (bf16_t)(acc[ddf][mf][3] * inv));
      *(ushort4*)(O + base + ddf * 16 + g * 4) = u;
    }
  }
}

// ---------------------------------------------------------------- launch
extern "C" void kernel_launch(void* const* d_in, const int* in_sizes, int n_in,
                              void* d_out, int out_size, void* d_ws, size_t ws_size,
                              hipStream_t stream) {
  const float* words     = (const float*)d_in[0];
  const float* position  = (const float*)d_in[1];
  const float* conscious = (const float*)d_in[2];
  const float* w_wq  = (const float*)d_in[3];
  const float* w_wk  = (const float*)d_in[4];
  const float* w_wv  = (const float*)d_in[5];
  const float* w_pq  = (const float*)d_in[6];
  const float* w_pk  = (const float*)d_in[7];
  const float* w_cq  = (const float*)d_in[8];
  const float* w_ck  = (const float*)d_in[9];
  const float* w_out = (const float*)d_in[10];
  const float* b_out = (const float*)d_in[11];

  char* ws = (char*)d_ws;
  bf16_t* Xcat = (bf16_t*)(ws);                 // 48 MiB
  bf16_t* Wqt  = (bf16_t*)(ws + 50331648);      // 6 MiB
  bf16_t* Wkt  = (bf16_t*)(ws + 56623104);      // 6 MiB
  bf16_t* Wvt  = (bf16_t*)(ws + 62914560);      // 2 MiB
  bf16_t* Wot  = (bf16_t*)(ws + 65011712);      // 2 MiB
  bf16_t* Qb   = (bf16_t*)(ws + 67108864);      // 16 MiB [B,H,N,D]
  bf16_t* Kbf  = (bf16_t*)(ws + 83886080);      // 16 MiB [B,H,N,D]
  bf16_t* Vtb  = (bf16_t*)(ws + 100663296);     // 16 MiB [B,H,D,N]
  bf16_t* Ob   = (bf16_t*)(ws + 117440512);     // 16 MiB [B,N,H*D]

  cast_concat<<<24576, 256, 0, stream>>>(words, position, conscious, Xcat);

  dim3 tb(32, 8), tg(32, 32);
  transpose_w<<<tg, tb, 0, stream>>>(w_wq,  Wqt, 3072, 0);
  transpose_w<<<tg, tb, 0, stream>>>(w_pq,  Wqt, 3072, 1024);
  transpose_w<<<tg, tb, 0, stream>>>(w_cq,  Wqt, 3072, 2048);
  transpose_w<<<tg, tb, 0, stream>>>(w_wk,  Wkt, 3072, 0);
  transpose_w<<<tg, tb, 0, stream>>>(w_pk,  Wkt, 3072, 1024);
  transpose_w<<<tg, tb, 0, stream>>>(w_ck,  Wkt, 3072, 2048);
  transpose_w<<<tg, tb, 0, stream>>>(w_wv,  Wvt, 1024, 0);
  transpose_w<<<tg, tb, 0, stream>>>(w_out, Wot, 1024, 0);

  dim3 gg(8, 64);  // N/128, M/128
  // Q scale: 1/sqrt(64) * log2(e)  (softmax runs in exp2 domain)
  gemm_bt<0><<<gg, 256, 0, stream>>>(Xcat, 3072, Wqt, 3072, Qb,  nullptr, 0.125f * 1.44269504f);
  gemm_bt<0><<<gg, 256, 0, stream>>>(Xcat, 3072, Wkt, 3072, Kbf, nullptr, 1.0f);
  gemm_bt<1><<<gg, 256, 0, stream>>>(Xcat, 3072, Wvt, 1024, Vtb, nullptr, 1.0f);

  attn_kernel<<<1024, 256, 0, stream>>>(Qb, Kbf, Vtb, Ob);

  gemm_bt<2><<<gg, 256, 0, stream>>>(Ob, 1024, Wot, 1024, (float*)d_out, b_out, 1.0f);
}

// Round 5
// 330.576 us; speedup vs baseline: 1.4329x; 1.1273x over previous
//
#include <hip/hip_runtime.h>
#include <hip/hip_bf16.h>

typedef __bf16 bf16_t;
typedef __attribute__((ext_vector_type(8))) __bf16 bf16x8;
typedef __attribute__((ext_vector_type(4))) float f32x4;
typedef __attribute__((ext_vector_type(16))) float f32x16;

__device__ __forceinline__ void gld_lds16(const void* g, void* l) {
  __builtin_amdgcn_global_load_lds((const __attribute__((address_space(1))) void*)g,
                                   (__attribute__((address_space(3))) void*)l, 16, 0, 0);
}

// ---------------------------------------------------------------- cast+concat
// Xcat[8192][3072] bf16 = [words | position | conscious]
__global__ __launch_bounds__(256) void cast_concat(
    const float* __restrict__ w, const float* __restrict__ p,
    const float* __restrict__ c, bf16_t* __restrict__ X)
{
  unsigned idx = blockIdx.x * 256u + threadIdx.x;   // one 4-float chunk
  unsigned src = idx >> 21;                         // 8192*256 = 2^21 chunks/source
  unsigned rem = idx & ((1u << 21) - 1);
  unsigned row = rem >> 8;
  unsigned k4  = (rem & 255u) * 4u;
  const float* s = (src == 0) ? w : (src == 1) ? p : c;
  f32x4 v = *(const f32x4*)(s + (size_t)row * 1024 + k4);
  ushort4 u;
  u.x = __builtin_bit_cast(unsigned short, (bf16_t)v[0]);
  u.y = __builtin_bit_cast(unsigned short, (bf16_t)v[1]);
  u.z = __builtin_bit_cast(unsigned short, (bf16_t)v[2]);
  u.w = __builtin_bit_cast(unsigned short, (bf16_t)v[3]);
  *(ushort4*)(X + (size_t)row * 3072 + src * 1024 + k4) = u;
}

// ---------------------------------------------------------------- W transpose (all 8 fused)
__global__ __launch_bounds__(256) void transpose_all(
    const float* __restrict__ w_wq, const float* __restrict__ w_pq,
    const float* __restrict__ w_cq, const float* __restrict__ w_wk,
    const float* __restrict__ w_pk, const float* __restrict__ w_ck,
    const float* __restrict__ w_wv, const float* __restrict__ w_out,
    bf16_t* __restrict__ Wqkt, bf16_t* __restrict__ Wvt, bf16_t* __restrict__ Wot)
{
  __shared__ float t[32][33];
  const int z = blockIdx.z;
  const float* src; bf16_t* dst; int dstride, koff, roff;
  switch (z) {
    case 0: src = w_wq;  dst = Wqkt; dstride = 3072; koff = 0;    roff = 0;    break;
    case 1: src = w_pq;  dst = Wqkt; dstride = 3072; koff = 1024; roff = 0;    break;
    case 2: src = w_cq;  dst = Wqkt; dstride = 3072; koff = 2048; roff = 0;    break;
    case 3: src = w_wk;  dst = Wqkt; dstride = 3072; koff = 0;    roff = 1024; break;
    case 4: src = w_pk;  dst = Wqkt; dstride = 3072; koff = 1024; roff = 1024; break;
    case 5: src = w_ck;  dst = Wqkt; dstride = 3072; koff = 2048; roff = 1024; break;
    case 6: src = w_wv;  dst = Wvt;  dstride = 1024; koff = 0;    roff = 0;    break;
    default: src = w_out; dst = Wot; dstride = 1024; koff = 0;    roff = 0;    break;
  }
  int bx = blockIdx.x, by = blockIdx.y;
  int x = bx * 32 + threadIdx.x;
  int y0 = by * 32;
  for (int i = threadIdx.y; i < 32; i += 8)
    t[i][threadIdx.x] = src[(size_t)(y0 + i) * 1024 + x];
  __syncthreads();
  int n0 = bx * 32;
  for (int i = threadIdx.y; i < 32; i += 8)
    dst[(size_t)(n0 + i + roff) * dstride + koff + y0 + threadIdx.x] =
        (bf16_t)t[threadIdx.x][i];
}

// ---------------------------------------------------------------- GEMM (B^T)
// EPI 0: merged Q|K epilogue -> Cout (Q, scaled) for col<1024, Cout2 (K) else.
// EPI 1: bf16 out to V^T [B,H,D,N].   EPI 2: f32 out row-major + bias.
template<int EPI>
__global__ __launch_bounds__(256, 2) void gemm_bt(
    const bf16_t* __restrict__ A, int lda,
    const bf16_t* __restrict__ Bt, int K,
    void* __restrict__ Cout, void* __restrict__ Cout2,
    const float* __restrict__ bias, float scale)
{
  __shared__ bf16_t As[128 * 32];
  __shared__ bf16_t Bs[128 * 32];
  const int tid  = threadIdx.x;
  const int wave = tid >> 6, lane = tid & 63;
  const int m0 = blockIdx.y * 128, n0 = blockIdx.x * 128;
  const int wr = (wave >> 1) * 64, wc = (wave & 1) * 64;
  const int lrow = lane & 15, lch = lane >> 4;

  f32x4 acc[4][4] = {};

  for (int k0 = 0; k0 < K; k0 += 32) {
    __syncthreads();
#pragma unroll
    for (int t = 0; t < 2; ++t) {
      int cc = t * 256 + tid;
      int row = cc >> 2, pp = cc & 3;
      int kswz = (pp ^ (row & 3)) * 8;
      gld_lds16(A  + (size_t)(m0 + row) * lda + k0 + kswz, &As[cc * 8]);
      gld_lds16(Bt + (size_t)(n0 + row) * K   + k0 + kswz, &Bs[cc * 8]);
    }
    __syncthreads();
    bf16x8 a[4], b[4];
#pragma unroll
    for (int i = 0; i < 4; ++i) {
      int r = wr + i * 16 + lrow;
      a[i] = *(const bf16x8*)&As[r * 32 + ((lch ^ (r & 3)) * 8)];
    }
#pragma unroll
    for (int i = 0; i < 4; ++i) {
      int r = wc + i * 16 + lrow;
      b[i] = *(const bf16x8*)&Bs[r * 32 + ((lch ^ (r & 3)) * 8)];
    }
#pragma unroll
    for (int i = 0; i < 4; ++i)
#pragma unroll
      for (int j = 0; j < 4; ++j)
        acc[i][j] = __builtin_amdgcn_mfma_f32_16x16x32_bf16(a[i], b[j], acc[i][j], 0, 0, 0);
  }

  const int g = lane >> 4, cl = lane & 15;
  if (EPI == 0) {
    bf16_t* Qo = (bf16_t*)Cout;
    bf16_t* Ko = (bf16_t*)Cout2;
#pragma unroll
    for (int i = 0; i < 4; ++i) {
      int m_base = m0 + wr + i * 16 + g * 4;
      int bb = m_base >> 11, nn = m_base & 2047;
#pragma unroll
      for (int j = 0; j < 4; ++j) {
        int col = n0 + wc + j * 16 + cl;
        bf16_t* dst = (col < 1024) ? Qo : Ko;
        int cc2 = col & 1023;
        float sc = (col < 1024) ? scale : 1.0f;
        int h = cc2 >> 6, d = cc2 & 63;
        size_t base = ((size_t)(bb * 16 + h) * 2048 + nn) * 64 + d;
#pragma unroll
        for (int r = 0; r < 4; ++r)
          dst[base + (size_t)r * 64] = (bf16_t)(acc[i][j][r] * sc);
      }
    }
  } else if (EPI == 1) {
    bf16_t* Vo = (bf16_t*)Cout;
#pragma unroll
    for (int i = 0; i < 4; ++i) {
      int m_base = m0 + wr + i * 16 + g * 4;
      int bb = m_base >> 11, nn = m_base & 2047;
#pragma unroll
      for (int j = 0; j < 4; ++j) {
        int col = n0 + wc + j * 16 + cl;
        int h = col >> 6, d = col & 63;
        ushort4 u;
        u.x = __builtin_bit_cast(unsigned short, (bf16_t)acc[i][j][0]);
        u.y = __builtin_bit_cast(unsigned short, (bf16_t)acc[i][j][1]);
        u.z = __builtin_bit_cast(unsigned short, (bf16_t)acc[i][j][2]);
        u.w = __builtin_bit_cast(unsigned short, (bf16_t)acc[i][j][3]);
        *(ushort4*)(Vo + ((size_t)(bb * 16 + h) * 64 + d) * 2048 + nn) = u;
      }
    }
  } else {
    float* Co = (float*)Cout;
#pragma unroll
    for (int i = 0; i < 4; ++i) {
      int m_base = m0 + wr + i * 16 + g * 4;
#pragma unroll
      for (int j = 0; j < 4; ++j) {
        int col = n0 + wc + j * 16 + cl;
        float bv = bias[col];
#pragma unroll
        for (int r = 0; r < 4; ++r)
          Co[(size_t)(m_base + r) * 1024 + col] = acc[i][j][r] + bv;
      }
    }
  }
}

// ---------------------------------------------------------------- attention v3
// 8 waves x 32 q-rows (QBLK=256), KVBLK=64, 32x32x16 MFMA, in-register P (T12).
// S^T = mfma(K,Q): q = lane&31 -> lane-local softmax; P B-frags via
// cvt_pk_bf16_f32 + permlane32_swap; PV = mfma(V^T, P) -> out^T, q = lane&31.
// K/V double-buffered via global_load_lds with counted vmcnt across raw barrier.
__global__ __launch_bounds__(512, 2) void attn_kernel(
    const bf16_t* __restrict__ Q, const bf16_t* __restrict__ Kb,
    const bf16_t* __restrict__ Vt, bf16_t* __restrict__ O)
{
  __shared__ bf16_t Ks[2][64 * 64];
  __shared__ bf16_t Vs[2][64 * 64];

  // XCD swizzle: 512 blocks = 8 XCDs x 64 -> 8 heads per XCD (KV 4MB = L2)
  const int fid = blockIdx.x;
  const int swz = (fid & 7) * 64 + (fid >> 3);
  const int bh = swz >> 3, qt = swz & 7;
  const int bb = bh >> 4, h = bh & 15;

  const int tid = threadIdx.x, wave = tid >> 6, lane = tid & 63;
  const int lq = lane & 31;   // q ownership / MFMA m,n row
  const int lh = lane >> 5;   // half-wave

  const bf16_t* Qb    = Q  + ((size_t)bh * 2048 + qt * 256) * 64;
  const bf16_t* Kbase = Kb + (size_t)bh * 2048 * 64;
  const bf16_t* Vbase = Vt + (size_t)bh * 64 * 2048;

  auto STAGE = [&](int buf, int kv0) {
    int row = tid >> 3, pp = tid & 7;               // 512 threads cover 64 rows x 8 granules
    int sgr = (pp ^ (row & 7)) * 8;                 // pre-swizzled global source (rule #21)
    gld_lds16(Kbase + (size_t)(kv0 + row) * 64 + sgr, &Ks[buf][tid * 8]);
    gld_lds16(Vbase + (size_t)row * 2048 + kv0 + sgr, &Vs[buf][tid * 8]);
  };

  STAGE(0, 0);

  // Q fragments: q = lane&31, k = kf*16 + lh*8 + i   (scale*log2e folded into Q)
  bf16x8 qf[4];
#pragma unroll
  for (int kf = 0; kf < 4; ++kf)
    qf[kf] = *(const bf16x8*)(Qb + (size_t)(wave * 32 + lq) * 64 + kf * 16 + lh * 8);

  f32x16 acc[2] = {};            // out^T: d = db*32 + (reg&3)+8*(reg>>2)+4*lh, q = lq
  float m_run = -1.0e30f, l_run = 0.f;

  for (int t = 0; t < 32; ++t) {
    const int buf = t & 1;
    if (t < 31) {
      STAGE(buf ^ 1, (t + 1) * 64);
      asm volatile("s_waitcnt vmcnt(2)" ::: "memory");   // stage-t done, t+1 in flight
    } else {
      asm volatile("s_waitcnt vmcnt(0)" ::: "memory");
    }
    __builtin_amdgcn_s_barrier();
    asm volatile("" ::: "memory");

    // S^T = K Q^T : st[nb], kv = nb*32 + (reg&3)+8*(reg>>2)+4*lh, q = lq
    f32x16 st[2] = {};
#pragma unroll
    for (int nb = 0; nb < 2; ++nb) {
      int r = nb * 32 + lq;
#pragma unroll
      for (int kf = 0; kf < 4; ++kf) {
        bf16x8 ka = *(const bf16x8*)&Ks[buf][r * 64 + (((kf * 2 + lh) ^ (r & 7)) * 8)];
        st[nb] = __builtin_amdgcn_mfma_f32_32x32x16_bf16(ka, qf[kf], st[nb], 0, 0, 0);
      }
    }

    // online softmax, lane-local (log2 domain)
    float tmax = st[0][0];
#pragma unroll
    for (int nb = 0; nb < 2; ++nb)
#pragma unroll
      for (int rg = 0; rg < 16; ++rg)
        tmax = fmaxf(tmax, st[nb][rg]);
    tmax = fmaxf(tmax, __shfl_xor(tmax, 32));

    if (!__all(tmax <= m_run + 8.0f)) {              // defer-rescale (T13)
      float mnew = fmaxf(m_run, tmax);
      float corr = __builtin_amdgcn_exp2f(m_run - mnew);
      m_run = mnew;
      l_run *= corr;
#pragma unroll
      for (int db = 0; db < 2; ++db)
#pragma unroll
        for (int rg = 0; rg < 16; ++rg)
          acc[db][rg] *= corr;
    }

    float sm = 0.f;
#pragma unroll
    for (int nb = 0; nb < 2; ++nb)
#pragma unroll
      for (int rg = 0; rg < 16; ++rg) {
        float p = __builtin_amdgcn_exp2f(st[nb][rg] - m_run);
        st[nb][rg] = p;
        sm += p;
      }
    sm += __shfl_xor(sm, 32);
    l_run += sm;

    // P B-frags in-register (T12) + PV
#pragma unroll
    for (int ks = 0; ks < 4; ++ks) {
      const int nb = ks >> 1;
      const int R = (ks & 1) * 8;
      unsigned x0, x1, y0, y1;
      asm("v_cvt_pk_bf16_f32 %0, %1, %2" : "=v"(x0) : "v"(st[nb][R + 0]), "v"(st[nb][R + 1]));
      asm("v_cvt_pk_bf16_f32 %0, %1, %2" : "=v"(x1) : "v"(st[nb][R + 2]), "v"(st[nb][R + 3]));
      asm("v_cvt_pk_bf16_f32 %0, %1, %2" : "=v"(y0) : "v"(st[nb][R + 4]), "v"(st[nb][R + 5]));
      asm("v_cvt_pk_bf16_f32 %0, %1, %2" : "=v"(y1) : "v"(st[nb][R + 6]), "v"(st[nb][R + 7]));
      asm volatile("v_permlane32_swap_b32 %0, %1" : "+v"(x0), "+v"(y0));
      asm volatile("v_permlane32_swap_b32 %0, %1" : "+v"(x1), "+v"(y1));
      int4 pw;
      pw.x = (int)x0; pw.y = (int)x1; pw.z = (int)y0; pw.w = (int)y1;
      bf16x8 pb = __builtin_bit_cast(bf16x8, pw);    // B-frag: k=kv=ks*16+lh*8+j, n=q
#pragma unroll
      for (int db = 0; db < 2; ++db) {
        int r = db * 32 + lq;
        bf16x8 va = *(const bf16x8*)&Vs[buf][r * 64 + (((ks * 2 + lh) ^ (r & 7)) * 8)];
        acc[db] = __builtin_amdgcn_mfma_f32_32x32x16_bf16(va, pb, acc[db], 0, 0, 0);
      }
    }

    asm volatile("s_waitcnt lgkmcnt(0)" ::: "memory"); // my LDS reads of buf done
    __builtin_amdgcn_s_barrier();                      // all waves done -> buf reusable
    asm volatile("" ::: "memory");
  }

  // normalize + write O[B, N, H*D] (8B packed stores)
  float inv = 1.0f / l_run;
  int nn = qt * 256 + wave * 32 + lq;
  size_t obase = ((size_t)bb * 2048 + nn) * 1024 + h * 64;
#pragma unroll
  for (int db = 0; db < 2; ++db)
#pragma unroll
    for (int rr = 0; rr < 4; ++rr) {                   // d = db*32 + rr*8 + lh*4 + (0..3)
      ushort4 u;
      u.x = __builtin_bit_cast(unsigned short, (bf16_t)(acc[db][rr * 4 + 0] * inv));
      u.y = __builtin_bit_cast(unsigned short, (bf16_t)(acc[db][rr * 4 + 1] * inv));
      u.z = __builtin_bit_cast(unsigned short, (bf16_t)(acc[db][rr * 4 + 2] * inv));
      u.w = __builtin_bit_cast(unsigned short, (bf16_t)(acc[db][rr * 4 + 3] * inv));
      *(ushort4*)(O + obase + db * 32 + rr * 8 + lh * 4) = u;
    }
}

// ---------------------------------------------------------------- launch
extern "C" void kernel_launch(void* const* d_in, const int* in_sizes, int n_in,
                              void* d_out, int out_size, void* d_ws, size_t ws_size,
                              hipStream_t stream) {
  const float* words     = (const float*)d_in[0];
  const float* position  = (const float*)d_in[1];
  const float* conscious = (const float*)d_in[2];
  const float* w_wq  = (const float*)d_in[3];
  const float* w_wk  = (const float*)d_in[4];
  const float* w_wv  = (const float*)d_in[5];
  const float* w_pq  = (const float*)d_in[6];
  const float* w_pk  = (const float*)d_in[7];
  const float* w_cq  = (const float*)d_in[8];
  const float* w_ck  = (const float*)d_in[9];
  const float* w_out = (const float*)d_in[10];
  const float* b_out = (const float*)d_in[11];

  char* ws = (char*)d_ws;
  bf16_t* Xcat = (bf16_t*)(ws);                 // 48 MiB [8192][3072]
  bf16_t* Wqkt = (bf16_t*)(ws + 50331648);      // 12 MiB [2048][3072]  (Q rows 0-1023, K rows 1024-2047)
  bf16_t* Wvt  = (bf16_t*)(ws + 62914560);      // 2 MiB  [1024][1024]
  bf16_t* Wot  = (bf16_t*)(ws + 65011712);      // 2 MiB  [1024][1024]
  bf16_t* Qb   = (bf16_t*)(ws + 67108864);      // 16 MiB [B,H,N,D]
  bf16_t* Kbf  = (bf16_t*)(ws + 83886080);      // 16 MiB [B,H,N,D]
  bf16_t* Vtb  = (bf16_t*)(ws + 100663296);     // 16 MiB [B,H,D,N]
  bf16_t* Ob   = (bf16_t*)(ws + 117440512);     // 16 MiB [B,N,H*D]

  cast_concat<<<24576, 256, 0, stream>>>(words, position, conscious, Xcat);

  transpose_all<<<dim3(32, 32, 8), dim3(32, 8), 0, stream>>>(
      w_wq, w_pq, w_cq, w_wk, w_pk, w_ck, w_wv, w_out, Wqkt, Wvt, Wot);

  // merged Q|K GEMM: N=2048; Q scale = 1/sqrt(64) * log2(e) (exp2-domain softmax)
  gemm_bt<0><<<dim3(16, 64), 256, 0, stream>>>(Xcat, 3072, Wqkt, 3072, Qb, Kbf,
                                               nullptr, 0.125f * 1.44269504f);
  gemm_bt<1><<<dim3(8, 64), 256, 0, stream>>>(Xcat, 3072, Wvt, 1024, Vtb, nullptr,
                                              nullptr, 1.0f);

  attn_kernel<<<512, 512, 0, stream>>>(Qb, Kbf, Vtb, Ob);

  gemm_bt<2><<<dim3(8, 64), 256, 0, stream>>>(Ob, 1024, Wot, 1024, (float*)d_out, nullptr,
                                              b_out, 1.0f);
}

// Round 6
// 296.787 us; speedup vs baseline: 1.5961x; 1.1138x over previous
//
#include <hip/hip_runtime.h>
#include <hip/hip_bf16.h>

typedef __bf16 bf16_t;
typedef __attribute__((ext_vector_type(8))) __bf16 bf16x8;
typedef __attribute__((ext_vector_type(4))) float f32x4;
typedef __attribute__((ext_vector_type(16))) float f32x16;

__device__ __forceinline__ void gld_lds16(const void* g, void* l) {
  __builtin_amdgcn_global_load_lds((const __attribute__((address_space(1))) void*)g,
                                   (__attribute__((address_space(3))) void*)l, 16, 0, 0);
}

// ---------------------------------------------------------------- cast+concat
// Xcat[8192][3072] bf16 = [words | position | conscious]
__global__ __launch_bounds__(256) void cast_concat(
    const float* __restrict__ w, const float* __restrict__ p,
    const float* __restrict__ c, bf16_t* __restrict__ X)
{
  unsigned idx = blockIdx.x * 256u + threadIdx.x;   // one 4-float chunk
  unsigned src = idx >> 21;                         // 8192*256 = 2^21 chunks/source
  unsigned rem = idx & ((1u << 21) - 1);
  unsigned row = rem >> 8;
  unsigned k4  = (rem & 255u) * 4u;
  const float* s = (src == 0) ? w : (src == 1) ? p : c;
  f32x4 v = *(const f32x4*)(s + (size_t)row * 1024 + k4);
  ushort4 u;
  u.x = __builtin_bit_cast(unsigned short, (bf16_t)v[0]);
  u.y = __builtin_bit_cast(unsigned short, (bf16_t)v[1]);
  u.z = __builtin_bit_cast(unsigned short, (bf16_t)v[2]);
  u.w = __builtin_bit_cast(unsigned short, (bf16_t)v[3]);
  *(ushort4*)(X + (size_t)row * 3072 + src * 1024 + k4) = u;
}

// ---------------------------------------------------------------- W transpose (all 8 fused)
__global__ __launch_bounds__(256) void transpose_all(
    const float* __restrict__ w_wq, const float* __restrict__ w_pq,
    const float* __restrict__ w_cq, const float* __restrict__ w_wk,
    const float* __restrict__ w_pk, const float* __restrict__ w_ck,
    const float* __restrict__ w_wv, const float* __restrict__ w_out,
    bf16_t* __restrict__ Wqkt, bf16_t* __restrict__ Wvt, bf16_t* __restrict__ Wot)
{
  __shared__ float t[32][33];
  const int z = blockIdx.z;
  const float* src; bf16_t* dst; int dstride, koff, roff;
  switch (z) {
    case 0: src = w_wq;  dst = Wqkt; dstride = 3072; koff = 0;    roff = 0;    break;
    case 1: src = w_pq;  dst = Wqkt; dstride = 3072; koff = 1024; roff = 0;    break;
    case 2: src = w_cq;  dst = Wqkt; dstride = 3072; koff = 2048; roff = 0;    break;
    case 3: src = w_wk;  dst = Wqkt; dstride = 3072; koff = 0;    roff = 1024; break;
    case 4: src = w_pk;  dst = Wqkt; dstride = 3072; koff = 1024; roff = 1024; break;
    case 5: src = w_ck;  dst = Wqkt; dstride = 3072; koff = 2048; roff = 1024; break;
    case 6: src = w_wv;  dst = Wvt;  dstride = 1024; koff = 0;    roff = 0;    break;
    default: src = w_out; dst = Wot; dstride = 1024; koff = 0;    roff = 0;    break;
  }
  int bx = blockIdx.x, by = blockIdx.y;
  int x = bx * 32 + threadIdx.x;
  int y0 = by * 32;
  for (int i = threadIdx.y; i < 32; i += 8)
    t[i][threadIdx.x] = src[(size_t)(y0 + i) * 1024 + x];
  __syncthreads();
  int n0 = bx * 32;
  for (int i = threadIdx.y; i < 32; i += 8)
    dst[(size_t)(n0 + i + roff) * dstride + koff + y0 + threadIdx.x] =
        (bf16_t)t[threadIdx.x][i];
}

// ---------------------------------------------------------------- GEMM 256x256 (B^T), merged Q|K epilogue
// 8 waves (2Mx4N), BK=64, 128 KiB LDS double-buffer, counted vmcnt(8) pipeline,
// full (r&7) XOR swizzle (conflict-free reads), setprio around MFMA cluster.
__global__ __launch_bounds__(512, 2) void gemm256_qk(
    const bf16_t* __restrict__ A, int lda,
    const bf16_t* __restrict__ Bt, int K,
    bf16_t* __restrict__ Qo, bf16_t* __restrict__ Ko, float scale, int nbx)
{
  __shared__ bf16_t As[2][256 * 64];
  __shared__ bf16_t Bs[2][256 * 64];

  const int tid = threadIdx.x;
  const int wave = tid >> 6, lane = tid & 63;
  const int wm = wave >> 2, wn = wave & 3;      // 2 x 4 wave grid
  const int lrow = lane & 15, lch = lane >> 4;

  // XCD-bijective swizzle: gridDim.x % 8 == 0 by construction
  const int nwg = gridDim.x, cpx = nwg >> 3;
  const int id  = blockIdx.x;
  const int swz = (id & 7) * cpx + (id >> 3);
  const int mb = swz / nbx, nb = swz % nbx;
  const int m0 = mb * 256, n0 = nb * 256;

  const int srow = tid >> 3, spp = tid & 7;     // staging: 64 rows x 8 granules / instr

  auto STAGE = [&](int buf, int k0) {
#pragma unroll
    for (int i = 0; i < 4; ++i) {
      int r = i * 64 + srow;
      int gsw = (spp ^ (r & 7)) * 8;            // pre-swizzled global source (rule #21)
      gld_lds16(A + (size_t)(m0 + r) * lda + k0 + gsw, &As[buf][r * 64 + spp * 8]);
    }
#pragma unroll
    for (int i = 0; i < 4; ++i) {
      int r = i * 64 + srow;
      int gsw = (spp ^ (r & 7)) * 8;
      gld_lds16(Bt + (size_t)(n0 + r) * K + k0 + gsw, &Bs[buf][r * 64 + spp * 8]);
    }
  };

  const int NT = K >> 6;                        // 48 for K=3072
  STAGE(0, 0);
  STAGE(1, 64);

  f32x4 acc[8][4] = {};

  for (int kt = 0; kt < NT; ++kt) {
    const int cur = kt & 1;
    if (kt < NT - 1) {
      asm volatile("s_waitcnt vmcnt(8)" ::: "memory");   // tile kt done, kt+1 in flight
    } else {
      asm volatile("s_waitcnt vmcnt(0)" ::: "memory");
    }
    asm volatile("s_barrier" ::: "memory");

#pragma unroll
    for (int ks = 0; ks < 2; ++ks) {
      bf16x8 af[8], bfr[4];
#pragma unroll
      for (int m = 0; m < 8; ++m) {
        int r = wm * 128 + m * 16 + lrow;
        af[m] = *(const bf16x8*)&As[cur][r * 64 + (((ks * 4 + lch) ^ (r & 7)) * 8)];
      }
#pragma unroll
      for (int n = 0; n < 4; ++n) {
        int r = wn * 64 + n * 16 + lrow;
        bfr[n] = *(const bf16x8*)&Bs[cur][r * 64 + (((ks * 4 + lch) ^ (r & 7)) * 8)];
      }
      __builtin_amdgcn_s_setprio(1);
#pragma unroll
      for (int m = 0; m < 8; ++m)
#pragma unroll
        for (int n = 0; n < 4; ++n)
          acc[m][n] = __builtin_amdgcn_mfma_f32_16x16x32_bf16(af[m], bfr[n], acc[m][n], 0, 0, 0);
      __builtin_amdgcn_s_setprio(0);
    }

    asm volatile("s_waitcnt lgkmcnt(0)" ::: "memory");   // my reads of buf done
    asm volatile("s_barrier" ::: "memory");              // all waves done -> buf reusable
    if (kt + 2 < NT) STAGE(cur, (kt + 2) * 64);
  }

  // epilogue: Q (scaled, cols<1024) / K (cols>=1024) to [B,H,N,D]
  const int g = lane >> 4, cl = lane & 15;
#pragma unroll
  for (int m = 0; m < 8; ++m) {
    int m_base = m0 + wm * 128 + m * 16 + g * 4;
    int bb = m_base >> 11, nn = m_base & 2047;
#pragma unroll
    for (int n = 0; n < 4; ++n) {
      int col = n0 + wn * 64 + n * 16 + cl;
      bf16_t* dst = (col < 1024) ? Qo : Ko;
      int cc2 = col & 1023;
      float sc = (col < 1024) ? scale : 1.0f;
      int h = cc2 >> 6, d = cc2 & 63;
      size_t base = ((size_t)(bb * 16 + h) * 2048 + nn) * 64 + d;
#pragma unroll
      for (int r = 0; r < 4; ++r)
        dst[base + (size_t)r * 64] = (bf16_t)(acc[m][n][r] * sc);
    }
  }
}

// ---------------------------------------------------------------- GEMM 128x128 (B^T)
// EPI 1: bf16 out to V^T [B,H,D,N].   EPI 2: f32 out row-major + bias.
template<int EPI>
__global__ __launch_bounds__(256, 2) void gemm_bt(
    const bf16_t* __restrict__ A, int lda,
    const bf16_t* __restrict__ Bt, int K,
    void* __restrict__ Cout, const float* __restrict__ bias, float scale)
{
  __shared__ bf16_t As[128 * 32];
  __shared__ bf16_t Bs[128 * 32];
  const int tid  = threadIdx.x;
  const int wave = tid >> 6, lane = tid & 63;
  const int m0 = blockIdx.y * 128, n0 = blockIdx.x * 128;
  const int wr = (wave >> 1) * 64, wc = (wave & 1) * 64;
  const int lrow = lane & 15, lch = lane >> 4;

  f32x4 acc[4][4] = {};

  for (int k0 = 0; k0 < K; k0 += 32) {
    __syncthreads();
#pragma unroll
    for (int t = 0; t < 2; ++t) {
      int cc = t * 256 + tid;
      int row = cc >> 2, pp = cc & 3;
      int kswz = (pp ^ (row & 3)) * 8;
      gld_lds16(A  + (size_t)(m0 + row) * lda + k0 + kswz, &As[cc * 8]);
      gld_lds16(Bt + (size_t)(n0 + row) * K   + k0 + kswz, &Bs[cc * 8]);
    }
    __syncthreads();
    bf16x8 a[4], b[4];
#pragma unroll
    for (int i = 0; i < 4; ++i) {
      int r = wr + i * 16 + lrow;
      a[i] = *(const bf16x8*)&As[r * 32 + ((lch ^ (r & 3)) * 8)];
    }
#pragma unroll
    for (int i = 0; i < 4; ++i) {
      int r = wc + i * 16 + lrow;
      b[i] = *(const bf16x8*)&Bs[r * 32 + ((lch ^ (r & 3)) * 8)];
    }
#pragma unroll
    for (int i = 0; i < 4; ++i)
#pragma unroll
      for (int j = 0; j < 4; ++j)
        acc[i][j] = __builtin_amdgcn_mfma_f32_16x16x32_bf16(a[i], b[j], acc[i][j], 0, 0, 0);
  }

  const int g = lane >> 4, cl = lane & 15;
  if (EPI == 1) {
    bf16_t* Vo = (bf16_t*)Cout;
#pragma unroll
    for (int i = 0; i < 4; ++i) {
      int m_base = m0 + wr + i * 16 + g * 4;
      int bb = m_base >> 11, nn = m_base & 2047;
#pragma unroll
      for (int j = 0; j < 4; ++j) {
        int col = n0 + wc + j * 16 + cl;
        int h = col >> 6, d = col & 63;
        ushort4 u;
        u.x = __builtin_bit_cast(unsigned short, (bf16_t)acc[i][j][0]);
        u.y = __builtin_bit_cast(unsigned short, (bf16_t)acc[i][j][1]);
        u.z = __builtin_bit_cast(unsigned short, (bf16_t)acc[i][j][2]);
        u.w = __builtin_bit_cast(unsigned short, (bf16_t)acc[i][j][3]);
        *(ushort4*)(Vo + ((size_t)(bb * 16 + h) * 64 + d) * 2048 + nn) = u;
      }
    }
  } else {
    float* Co = (float*)Cout;
#pragma unroll
    for (int i = 0; i < 4; ++i) {
      int m_base = m0 + wr + i * 16 + g * 4;
#pragma unroll
      for (int j = 0; j < 4; ++j) {
        int col = n0 + wc + j * 16 + cl;
        float bv = bias[col];
#pragma unroll
        for (int r = 0; r < 4; ++r)
          Co[(size_t)(m_base + r) * 1024 + col] = acc[i][j][r] + bv;
      }
    }
  }
}

// ---------------------------------------------------------------- attention v3
// 8 waves x 32 q-rows (QBLK=256), KVBLK=64, 32x32x16 MFMA, in-register P (T12).
__global__ __launch_bounds__(512, 2) void attn_kernel(
    const bf16_t* __restrict__ Q, const bf16_t* __restrict__ Kb,
    const bf16_t* __restrict__ Vt, bf16_t* __restrict__ O)
{
  __shared__ bf16_t Ks[2][64 * 64];
  __shared__ bf16_t Vs[2][64 * 64];

  const int fid = blockIdx.x;
  const int swz = (fid & 7) * 64 + (fid >> 3);
  const int bh = swz >> 3, qt = swz & 7;
  const int bb = bh >> 4, h = bh & 15;

  const int tid = threadIdx.x, wave = tid >> 6, lane = tid & 63;
  const int lq = lane & 31;
  const int lh = lane >> 5;

  const bf16_t* Qb    = Q  + ((size_t)bh * 2048 + qt * 256) * 64;
  const bf16_t* Kbase = Kb + (size_t)bh * 2048 * 64;
  const bf16_t* Vbase = Vt + (size_t)bh * 64 * 2048;

  auto STAGE = [&](int buf, int kv0) {
    int row = tid >> 3, pp = tid & 7;
    int sgr = (pp ^ (row & 7)) * 8;
    gld_lds16(Kbase + (size_t)(kv0 + row) * 64 + sgr, &Ks[buf][tid * 8]);
    gld_lds16(Vbase + (size_t)row * 2048 + kv0 + sgr, &Vs[buf][tid * 8]);
  };

  STAGE(0, 0);

  bf16x8 qf[4];
#pragma unroll
  for (int kf = 0; kf < 4; ++kf)
    qf[kf] = *(const bf16x8*)(Qb + (size_t)(wave * 32 + lq) * 64 + kf * 16 + lh * 8);

  f32x16 acc[2] = {};
  float m_run = -1.0e30f, l_run = 0.f;

  for (int t = 0; t < 32; ++t) {
    const int buf = t & 1;
    if (t < 31) {
      STAGE(buf ^ 1, (t + 1) * 64);
      asm volatile("s_waitcnt vmcnt(2)" ::: "memory");
    } else {
      asm volatile("s_waitcnt vmcnt(0)" ::: "memory");
    }
    __builtin_amdgcn_s_barrier();
    asm volatile("" ::: "memory");

    f32x16 st[2] = {};
#pragma unroll
    for (int nb = 0; nb < 2; ++nb) {
      int r = nb * 32 + lq;
#pragma unroll
      for (int kf = 0; kf < 4; ++kf) {
        bf16x8 ka = *(const bf16x8*)&Ks[buf][r * 64 + (((kf * 2 + lh) ^ (r & 7)) * 8)];
        st[nb] = __builtin_amdgcn_mfma_f32_32x32x16_bf16(ka, qf[kf], st[nb], 0, 0, 0);
      }
    }

    float tmax = st[0][0];
#pragma unroll
    for (int nb = 0; nb < 2; ++nb)
#pragma unroll
      for (int rg = 0; rg < 16; ++rg)
        tmax = fmaxf(tmax, st[nb][rg]);
    tmax = fmaxf(tmax, __shfl_xor(tmax, 32));

    if (!__all(tmax <= m_run + 8.0f)) {
      float mnew = fmaxf(m_run, tmax);
      float corr = __builtin_amdgcn_exp2f(m_run - mnew);
      m_run = mnew;
      l_run *= corr;
#pragma unroll
      for (int db = 0; db < 2; ++db)
#pragma unroll
        for (int rg = 0; rg < 16; ++rg)
          acc[db][rg] *= corr;
    }

    float sm = 0.f;
#pragma unroll
    for (int nb = 0; nb < 2; ++nb)
#pragma unroll
      for (int rg = 0; rg < 16; ++rg) {
        float p = __builtin_amdgcn_exp2f(st[nb][rg] - m_run);
        st[nb][rg] = p;
        sm += p;
      }
    sm += __shfl_xor(sm, 32);
    l_run += sm;

#pragma unroll
    for (int ks = 0; ks < 4; ++ks) {
      const int nb = ks >> 1;
      const int R = (ks & 1) * 8;
      unsigned x0, x1, y0, y1;
      asm("v_cvt_pk_bf16_f32 %0, %1, %2" : "=v"(x0) : "v"(st[nb][R + 0]), "v"(st[nb][R + 1]));
      asm("v_cvt_pk_bf16_f32 %0, %1, %2" : "=v"(x1) : "v"(st[nb][R + 2]), "v"(st[nb][R + 3]));
      asm("v_cvt_pk_bf16_f32 %0, %1, %2" : "=v"(y0) : "v"(st[nb][R + 4]), "v"(st[nb][R + 5]));
      asm("v_cvt_pk_bf16_f32 %0, %1, %2" : "=v"(y1) : "v"(st[nb][R + 6]), "v"(st[nb][R + 7]));
      asm volatile("v_permlane32_swap_b32 %0, %1" : "+v"(x0), "+v"(y0));
      asm volatile("v_permlane32_swap_b32 %0, %1" : "+v"(x1), "+v"(y1));
      int4 pw;
      pw.x = (int)x0; pw.y = (int)x1; pw.z = (int)y0; pw.w = (int)y1;
      bf16x8 pb = __builtin_bit_cast(bf16x8, pw);
#pragma unroll
      for (int db = 0; db < 2; ++db) {
        int r = db * 32 + lq;
        bf16x8 va = *(const bf16x8*)&Vs[buf][r * 64 + (((ks * 2 + lh) ^ (r & 7)) * 8)];
        acc[db] = __builtin_amdgcn_mfma_f32_32x32x16_bf16(va, pb, acc[db], 0, 0, 0);
      }
    }

    asm volatile("s_waitcnt lgkmcnt(0)" ::: "memory");
    __builtin_amdgcn_s_barrier();
    asm volatile("" ::: "memory");
  }

  float inv = 1.0f / l_run;
  int nn = qt * 256 + wave * 32 + lq;
  size_t obase = ((size_t)bb * 2048 + nn) * 1024 + h * 64;
#pragma unroll
  for (int db = 0; db < 2; ++db)
#pragma unroll
    for (int rr = 0; rr < 4; ++rr) {
      ushort4 u;
      u.x = __builtin_bit_cast(unsigned short, (bf16_t)(acc[db][rr * 4 + 0] * inv));
      u.y = __builtin_bit_cast(unsigned short, (bf16_t)(acc[db][rr * 4 + 1] * inv));
      u.z = __builtin_bit_cast(unsigned short, (bf16_t)(acc[db][rr * 4 + 2] * inv));
      u.w = __builtin_bit_cast(unsigned short, (bf16_t)(acc[db][rr * 4 + 3] * inv));
      *(ushort4*)(O + obase + db * 32 + rr * 8 + lh * 4) = u;
    }
}

// ---------------------------------------------------------------- launch
extern "C" void kernel_launch(void* const* d_in, const int* in_sizes, int n_in,
                              void* d_out, int out_size, void* d_ws, size_t ws_size,
                              hipStream_t stream) {
  const float* words     = (const float*)d_in[0];
  const float* position  = (const float*)d_in[1];
  const float* conscious = (const float*)d_in[2];
  const float* w_wq  = (const float*)d_in[3];
  const float* w_wk  = (const float*)d_in[4];
  const float* w_wv  = (const float*)d_in[5];
  const float* w_pq  = (const float*)d_in[6];
  const float* w_pk  = (const float*)d_in[7];
  const float* w_cq  = (const float*)d_in[8];
  const float* w_ck  = (const float*)d_in[9];
  const float* w_out = (const float*)d_in[10];
  const float* b_out = (const float*)d_in[11];

  char* ws = (char*)d_ws;
  bf16_t* Xcat = (bf16_t*)(ws);                 // 48 MiB [8192][3072]
  bf16_t* Wqkt = (bf16_t*)(ws + 50331648);      // 12 MiB [2048][3072]
  bf16_t* Wvt  = (bf16_t*)(ws + 62914560);      // 2 MiB  [1024][1024]
  bf16_t* Wot  = (bf16_t*)(ws + 65011712);      // 2 MiB  [1024][1024]
  bf16_t* Qb   = (bf16_t*)(ws + 67108864);      // 16 MiB [B,H,N,D]
  bf16_t* Kbf  = (bf16_t*)(ws + 83886080);      // 16 MiB [B,H,N,D]
  bf16_t* Vtb  = (bf16_t*)(ws + 100663296);     // 16 MiB [B,H,D,N]
  bf16_t* Ob   = (bf16_t*)(ws + 117440512);     // 16 MiB [B,N,H*D]

  cast_concat<<<24576, 256, 0, stream>>>(words, position, conscious, Xcat);

  transpose_all<<<dim3(32, 32, 8), dim3(32, 8), 0, stream>>>(
      w_wq, w_pq, w_cq, w_wk, w_pk, w_ck, w_wv, w_out, Wqkt, Wvt, Wot);

  // merged Q|K GEMM: 256x256 tiles, 32x8 = 256 blocks (1/CU, no tail)
  gemm256_qk<<<256, 512, 0, stream>>>(Xcat, 3072, Wqkt, 3072, Qb, Kbf,
                                      0.125f * 1.44269504f, 8);
  gemm_bt<1><<<dim3(8, 64), 256, 0, stream>>>(Xcat, 3072, Wvt, 1024, Vtb, nullptr, 1.0f);

  attn_kernel<<<512, 512, 0, stream>>>(Qb, Kbf, Vtb, Ob);

  gemm_bt<2><<<dim3(8, 64), 256, 0, stream>>>(Ob, 1024, Wot, 1024, (float*)d_out,
                                              b_out, 1.0f);
}

// Round 7
// 288.866 us; speedup vs baseline: 1.6398x; 1.0274x over previous
//
#include <hip/hip_runtime.h>
#include <hip/hip_bf16.h>

typedef __bf16 bf16_t;
typedef __attribute__((ext_vector_type(8))) __bf16 bf16x8;
typedef __attribute__((ext_vector_type(4))) float f32x4;
typedef __attribute__((ext_vector_type(16))) float f32x16;

__device__ __forceinline__ void gld_lds16(const void* g, void* l) {
  __builtin_amdgcn_global_load_lds((const __attribute__((address_space(1))) void*)g,
                                   (__attribute__((address_space(3))) void*)l, 16, 0, 0);
}

// ---------------------------------------------------------------- cast+concat
// Xcat[8192][3072] bf16 = [words | position | conscious]
__global__ __launch_bounds__(256) void cast_concat(
    const float* __restrict__ w, const float* __restrict__ p,
    const float* __restrict__ c, bf16_t* __restrict__ X)
{
  unsigned idx = blockIdx.x * 256u + threadIdx.x;   // one 4-float chunk
  unsigned src = idx >> 21;                         // 8192*256 = 2^21 chunks/source
  unsigned rem = idx & ((1u << 21) - 1);
  unsigned row = rem >> 8;
  unsigned k4  = (rem & 255u) * 4u;
  const float* s = (src == 0) ? w : (src == 1) ? p : c;
  f32x4 v = *(const f32x4*)(s + (size_t)row * 1024 + k4);
  ushort4 u;
  u.x = __builtin_bit_cast(unsigned short, (bf16_t)v[0]);
  u.y = __builtin_bit_cast(unsigned short, (bf16_t)v[1]);
  u.z = __builtin_bit_cast(unsigned short, (bf16_t)v[2]);
  u.w = __builtin_bit_cast(unsigned short, (bf16_t)v[3]);
  *(ushort4*)(X + (size_t)row * 3072 + src * 1024 + k4) = u;
}

// ---------------------------------------------------------------- W transpose (all 8 fused)
__global__ __launch_bounds__(256) void transpose_all(
    const float* __restrict__ w_wq, const float* __restrict__ w_pq,
    const float* __restrict__ w_cq, const float* __restrict__ w_wk,
    const float* __restrict__ w_pk, const float* __restrict__ w_ck,
    const float* __restrict__ w_wv, const float* __restrict__ w_out,
    bf16_t* __restrict__ Wqkt, bf16_t* __restrict__ Wvt, bf16_t* __restrict__ Wot)
{
  __shared__ float t[32][33];
  const int z = blockIdx.z;
  const float* src; bf16_t* dst; int dstride, koff, roff;
  switch (z) {
    case 0: src = w_wq;  dst = Wqkt; dstride = 3072; koff = 0;    roff = 0;    break;
    case 1: src = w_pq;  dst = Wqkt; dstride = 3072; koff = 1024; roff = 0;    break;
    case 2: src = w_cq;  dst = Wqkt; dstride = 3072; koff = 2048; roff = 0;    break;
    case 3: src = w_wk;  dst = Wqkt; dstride = 3072; koff = 0;    roff = 1024; break;
    case 4: src = w_pk;  dst = Wqkt; dstride = 3072; koff = 1024; roff = 1024; break;
    case 5: src = w_ck;  dst = Wqkt; dstride = 3072; koff = 2048; roff = 1024; break;
    case 6: src = w_wv;  dst = Wvt;  dstride = 1024; koff = 0;    roff = 0;    break;
    default: src = w_out; dst = Wot; dstride = 1024; koff = 0;    roff = 0;    break;
  }
  int bx = blockIdx.x, by = blockIdx.y;
  int x = bx * 32 + threadIdx.x;
  int y0 = by * 32;
  for (int i = threadIdx.y; i < 32; i += 8)
    t[i][threadIdx.x] = src[(size_t)(y0 + i) * 1024 + x];
  __syncthreads();
  int n0 = bx * 32;
  for (int i = threadIdx.y; i < 32; i += 8)
    dst[(size_t)(n0 + i + roff) * dstride + koff + y0 + threadIdx.x] =
        (bf16_t)t[threadIdx.x][i];
}

// ---------------------------------------------------------------- GEMM 256x256 (B^T), merged Q|K epilogue
// 8 waves (2Mx4N), BK=64, 128 KiB LDS double-buffer, counted vmcnt(8) pipeline,
// full (r&7) XOR swizzle (conflict-free reads), setprio around MFMA cluster.
__global__ __launch_bounds__(512, 2) void gemm256_qk(
    const bf16_t* __restrict__ A, int lda,
    const bf16_t* __restrict__ Bt, int K,
    bf16_t* __restrict__ Qo, bf16_t* __restrict__ Ko, float scale, int nbx)
{
  __shared__ bf16_t As[2][256 * 64];
  __shared__ bf16_t Bs[2][256 * 64];

  const int tid = threadIdx.x;
  const int wave = tid >> 6, lane = tid & 63;
  const int wm = wave >> 2, wn = wave & 3;      // 2 x 4 wave grid
  const int lrow = lane & 15, lch = lane >> 4;

  const int nwg = gridDim.x, cpx = nwg >> 3;
  const int id  = blockIdx.x;
  const int swz = (id & 7) * cpx + (id >> 3);
  const int mb = swz / nbx, nb = swz % nbx;
  const int m0 = mb * 256, n0 = nb * 256;

  const int srow = tid >> 3, spp = tid & 7;     // staging: 64 rows x 8 granules / instr

  auto STAGE = [&](int buf, int k0) {
#pragma unroll
    for (int i = 0; i < 4; ++i) {
      int r = i * 64 + srow;
      int gsw = (spp ^ (r & 7)) * 8;            // pre-swizzled global source (rule #21)
      gld_lds16(A + (size_t)(m0 + r) * lda + k0 + gsw, &As[buf][r * 64 + spp * 8]);
    }
#pragma unroll
    for (int i = 0; i < 4; ++i) {
      int r = i * 64 + srow;
      int gsw = (spp ^ (r & 7)) * 8;
      gld_lds16(Bt + (size_t)(n0 + r) * K + k0 + gsw, &Bs[buf][r * 64 + spp * 8]);
    }
  };

  const int NT = K >> 6;                        // 48 for K=3072
  STAGE(0, 0);
  STAGE(1, 64);

  f32x4 acc[8][4] = {};

  for (int kt = 0; kt < NT; ++kt) {
    const int cur = kt & 1;
    if (kt < NT - 1) {
      asm volatile("s_waitcnt vmcnt(8)" ::: "memory");   // tile kt done, kt+1 in flight
    } else {
      asm volatile("s_waitcnt vmcnt(0)" ::: "memory");
    }
    asm volatile("s_barrier" ::: "memory");

#pragma unroll
    for (int ks = 0; ks < 2; ++ks) {
      bf16x8 af[8], bfr[4];
#pragma unroll
      for (int m = 0; m < 8; ++m) {
        int r = wm * 128 + m * 16 + lrow;
        af[m] = *(const bf16x8*)&As[cur][r * 64 + (((ks * 4 + lch) ^ (r & 7)) * 8)];
      }
#pragma unroll
      for (int n = 0; n < 4; ++n) {
        int r = wn * 64 + n * 16 + lrow;
        bfr[n] = *(const bf16x8*)&Bs[cur][r * 64 + (((ks * 4 + lch) ^ (r & 7)) * 8)];
      }
      __builtin_amdgcn_s_setprio(1);
#pragma unroll
      for (int m = 0; m < 8; ++m)
#pragma unroll
        for (int n = 0; n < 4; ++n)
          acc[m][n] = __builtin_amdgcn_mfma_f32_16x16x32_bf16(af[m], bfr[n], acc[m][n], 0, 0, 0);
      __builtin_amdgcn_s_setprio(0);
    }

    asm volatile("s_waitcnt lgkmcnt(0)" ::: "memory");   // my reads of buf done
    asm volatile("s_barrier" ::: "memory");              // all waves done -> buf reusable
    if (kt + 2 < NT) STAGE(cur, (kt + 2) * 64);
  }

  // epilogue: Q (scaled, cols<1024) / K (cols>=1024) to [B,H,N,D]
  const int g = lane >> 4, cl = lane & 15;
#pragma unroll
  for (int m = 0; m < 8; ++m) {
    int m_base = m0 + wm * 128 + m * 16 + g * 4;
    int bb = m_base >> 11, nn = m_base & 2047;
#pragma unroll
    for (int n = 0; n < 4; ++n) {
      int col = n0 + wn * 64 + n * 16 + cl;
      bf16_t* dst = (col < 1024) ? Qo : Ko;
      int cc2 = col & 1023;
      float sc = (col < 1024) ? scale : 1.0f;
      int h = cc2 >> 6, d = cc2 & 63;
      size_t base = ((size_t)(bb * 16 + h) * 2048 + nn) * 64 + d;
#pragma unroll
      for (int r = 0; r < 4; ++r)
        dst[base + (size_t)r * 64] = (bf16_t)(acc[m][n][r] * sc);
    }
  }
}

// ---------------------------------------------------------------- GEMM 128x256 (B^T), pipelined
// Same validated schedule as gemm256_qk, tile 128x256, 8 waves (2Mx4N), per-wave 64x64.
// Grid: 64 x 4 = 256 blocks (1/CU).  BK=64 dbuf = 96 KiB LDS, 6 loads/thread -> vmcnt(6).
// EPI 1: bf16 out to V^T [B,H,D,N].   EPI 2: f32 out row-major + bias.
template<int EPI>
__global__ __launch_bounds__(512, 2) void gemm128x256(
    const bf16_t* __restrict__ A, int lda,
    const bf16_t* __restrict__ Bt, int K,
    void* __restrict__ Cout, const float* __restrict__ bias)
{
  __shared__ bf16_t As[2][128 * 64];
  __shared__ bf16_t Bs[2][256 * 64];

  const int tid = threadIdx.x;
  const int wave = tid >> 6, lane = tid & 63;
  const int wm = wave >> 2, wn = wave & 3;      // 2 x 4 wave grid, per-wave 64x64
  const int lrow = lane & 15, lch = lane >> 4;

  const int nwg = gridDim.x, cpx = nwg >> 3;    // 256 blocks -> cpx=32
  const int id  = blockIdx.x;
  const int swz = (id & 7) * cpx + (id >> 3);
  const int mb = swz >> 2, nb = swz & 3;        // nbx = 4
  const int m0 = mb * 128, n0 = nb * 256;

  const int srow = tid >> 3, spp = tid & 7;

  auto STAGE = [&](int buf, int k0) {
#pragma unroll
    for (int i = 0; i < 2; ++i) {
      int r = i * 64 + srow;
      int gsw = (spp ^ (r & 7)) * 8;
      gld_lds16(A + (size_t)(m0 + r) * lda + k0 + gsw, &As[buf][r * 64 + spp * 8]);
    }
#pragma unroll
    for (int i = 0; i < 4; ++i) {
      int r = i * 64 + srow;
      int gsw = (spp ^ (r & 7)) * 8;
      gld_lds16(Bt + (size_t)(n0 + r) * K + k0 + gsw, &Bs[buf][r * 64 + spp * 8]);
    }
  };

  const int NT = K >> 6;                        // 16 for K=1024
  STAGE(0, 0);
  STAGE(1, 64);

  f32x4 acc[4][4] = {};

  for (int kt = 0; kt < NT; ++kt) {
    const int cur = kt & 1;
    if (kt < NT - 1) {
      asm volatile("s_waitcnt vmcnt(6)" ::: "memory");
    } else {
      asm volatile("s_waitcnt vmcnt(0)" ::: "memory");
    }
    asm volatile("s_barrier" ::: "memory");

#pragma unroll
    for (int ks = 0; ks < 2; ++ks) {
      bf16x8 af[4], bfr[4];
#pragma unroll
      for (int m = 0; m < 4; ++m) {
        int r = wm * 64 + m * 16 + lrow;
        af[m] = *(const bf16x8*)&As[cur][r * 64 + (((ks * 4 + lch) ^ (r & 7)) * 8)];
      }
#pragma unroll
      for (int n = 0; n < 4; ++n) {
        int r = wn * 64 + n * 16 + lrow;
        bfr[n] = *(const bf16x8*)&Bs[cur][r * 64 + (((ks * 4 + lch) ^ (r & 7)) * 8)];
      }
      __builtin_amdgcn_s_setprio(1);
#pragma unroll
      for (int m = 0; m < 4; ++m)
#pragma unroll
        for (int n = 0; n < 4; ++n)
          acc[m][n] = __builtin_amdgcn_mfma_f32_16x16x32_bf16(af[m], bfr[n], acc[m][n], 0, 0, 0);
      __builtin_amdgcn_s_setprio(0);
    }

    asm volatile("s_waitcnt lgkmcnt(0)" ::: "memory");
    asm volatile("s_barrier" ::: "memory");
    if (kt + 2 < NT) STAGE(cur, (kt + 2) * 64);
  }

  const int g = lane >> 4, cl = lane & 15;
  if (EPI == 1) {
    bf16_t* Vo = (bf16_t*)Cout;
#pragma unroll
    for (int m = 0; m < 4; ++m) {
      int m_base = m0 + wm * 64 + m * 16 + g * 4;
      int bb = m_base >> 11, nn = m_base & 2047;
#pragma unroll
      for (int n = 0; n < 4; ++n) {
        int col = n0 + wn * 64 + n * 16 + cl;
        int h = col >> 6, d = col & 63;
        ushort4 u;
        u.x = __builtin_bit_cast(unsigned short, (bf16_t)acc[m][n][0]);
        u.y = __builtin_bit_cast(unsigned short, (bf16_t)acc[m][n][1]);
        u.z = __builtin_bit_cast(unsigned short, (bf16_t)acc[m][n][2]);
        u.w = __builtin_bit_cast(unsigned short, (bf16_t)acc[m][n][3]);
        *(ushort4*)(Vo + ((size_t)(bb * 16 + h) * 64 + d) * 2048 + nn) = u;
      }
    }
  } else {
    float* Co = (float*)Cout;
#pragma unroll
    for (int m = 0; m < 4; ++m) {
      int m_base = m0 + wm * 64 + m * 16 + g * 4;
#pragma unroll
      for (int n = 0; n < 4; ++n) {
        int col = n0 + wn * 64 + n * 16 + cl;
        float bv = bias[col];
#pragma unroll
        for (int r = 0; r < 4; ++r)
          Co[(size_t)(m_base + r) * 1024 + col] = acc[m][n][r] + bv;
      }
    }
  }
}

// ---------------------------------------------------------------- attention v3
// 8 waves x 32 q-rows (QBLK=256), KVBLK=64, 32x32x16 MFMA, in-register P (T12).
__global__ __launch_bounds__(512, 2) void attn_kernel(
    const bf16_t* __restrict__ Q, const bf16_t* __restrict__ Kb,
    const bf16_t* __restrict__ Vt, bf16_t* __restrict__ O)
{
  __shared__ bf16_t Ks[2][64 * 64];
  __shared__ bf16_t Vs[2][64 * 64];

  const int fid = blockIdx.x;
  const int swz = (fid & 7) * 64 + (fid >> 3);
  const int bh = swz >> 3, qt = swz & 7;
  const int bb = bh >> 4, h = bh & 15;

  const int tid = threadIdx.x, wave = tid >> 6, lane = tid & 63;
  const int lq = lane & 31;
  const int lh = lane >> 5;

  const bf16_t* Qb    = Q  + ((size_t)bh * 2048 + qt * 256) * 64;
  const bf16_t* Kbase = Kb + (size_t)bh * 2048 * 64;
  const bf16_t* Vbase = Vt + (size_t)bh * 64 * 2048;

  auto STAGE = [&](int buf, int kv0) {
    int row = tid >> 3, pp = tid & 7;
    int sgr = (pp ^ (row & 7)) * 8;
    gld_lds16(Kbase + (size_t)(kv0 + row) * 64 + sgr, &Ks[buf][tid * 8]);
    gld_lds16(Vbase + (size_t)row * 2048 + kv0 + sgr, &Vs[buf][tid * 8]);
  };

  STAGE(0, 0);

  bf16x8 qf[4];
#pragma unroll
  for (int kf = 0; kf < 4; ++kf)
    qf[kf] = *(const bf16x8*)(Qb + (size_t)(wave * 32 + lq) * 64 + kf * 16 + lh * 8);

  f32x16 acc[2] = {};
  float m_run = -1.0e30f, l_run = 0.f;

  for (int t = 0; t < 32; ++t) {
    const int buf = t & 1;
    if (t < 31) {
      STAGE(buf ^ 1, (t + 1) * 64);
      asm volatile("s_waitcnt vmcnt(2)" ::: "memory");
    } else {
      asm volatile("s_waitcnt vmcnt(0)" ::: "memory");
    }
    __builtin_amdgcn_s_barrier();
    asm volatile("" ::: "memory");

    f32x16 st[2] = {};
#pragma unroll
    for (int nb = 0; nb < 2; ++nb) {
      int r = nb * 32 + lq;
#pragma unroll
      for (int kf = 0; kf < 4; ++kf) {
        bf16x8 ka = *(const bf16x8*)&Ks[buf][r * 64 + (((kf * 2 + lh) ^ (r & 7)) * 8)];
        st[nb] = __builtin_amdgcn_mfma_f32_32x32x16_bf16(ka, qf[kf], st[nb], 0, 0, 0);
      }
    }

    float tmax = st[0][0];
#pragma unroll
    for (int nb = 0; nb < 2; ++nb)
#pragma unroll
      for (int rg = 0; rg < 16; ++rg)
        tmax = fmaxf(tmax, st[nb][rg]);
    tmax = fmaxf(tmax, __shfl_xor(tmax, 32));

    if (!__all(tmax <= m_run + 8.0f)) {
      float mnew = fmaxf(m_run, tmax);
      float corr = __builtin_amdgcn_exp2f(m_run - mnew);
      m_run = mnew;
      l_run *= corr;
#pragma unroll
      for (int db = 0; db < 2; ++db)
#pragma unroll
        for (int rg = 0; rg < 16; ++rg)
          acc[db][rg] *= corr;
    }

    float sm = 0.f;
#pragma unroll
    for (int nb = 0; nb < 2; ++nb)
#pragma unroll
      for (int rg = 0; rg < 16; ++rg) {
        float p = __builtin_amdgcn_exp2f(st[nb][rg] - m_run);
        st[nb][rg] = p;
        sm += p;
      }
    sm += __shfl_xor(sm, 32);
    l_run += sm;

#pragma unroll
    for (int ks = 0; ks < 4; ++ks) {
      const int nb = ks >> 1;
      const int R = (ks & 1) * 8;
      unsigned x0, x1, y0, y1;
      asm("v_cvt_pk_bf16_f32 %0, %1, %2" : "=v"(x0) : "v"(st[nb][R + 0]), "v"(st[nb][R + 1]));
      asm("v_cvt_pk_bf16_f32 %0, %1, %2" : "=v"(x1) : "v"(st[nb][R + 2]), "v"(st[nb][R + 3]));
      asm("v_cvt_pk_bf16_f32 %0, %1, %2" : "=v"(y0) : "v"(st[nb][R + 4]), "v"(st[nb][R + 5]));
      asm("v_cvt_pk_bf16_f32 %0, %1, %2" : "=v"(y1) : "v"(st[nb][R + 6]), "v"(st[nb][R + 7]));
      asm volatile("v_permlane32_swap_b32 %0, %1" : "+v"(x0), "+v"(y0));
      asm volatile("v_permlane32_swap_b32 %0, %1" : "+v"(x1), "+v"(y1));
      int4 pw;
      pw.x = (int)x0; pw.y = (int)x1; pw.z = (int)y0; pw.w = (int)y1;
      bf16x8 pb = __builtin_bit_cast(bf16x8, pw);
#pragma unroll
      for (int db = 0; db < 2; ++db) {
        int r = db * 32 + lq;
        bf16x8 va = *(const bf16x8*)&Vs[buf][r * 64 + (((ks * 2 + lh) ^ (r & 7)) * 8)];
        acc[db] = __builtin_amdgcn_mfma_f32_32x32x16_bf16(va, pb, acc[db], 0, 0, 0);
      }
    }

    asm volatile("s_waitcnt lgkmcnt(0)" ::: "memory");
    __builtin_amdgcn_s_barrier();
    asm volatile("" ::: "memory");
  }

  float inv = 1.0f / l_run;
  int nn = qt * 256 + wave * 32 + lq;
  size_t obase = ((size_t)bb * 2048 + nn) * 1024 + h * 64;
#pragma unroll
  for (int db = 0; db < 2; ++db)
#pragma unroll
    for (int rr = 0; rr < 4; ++rr) {
      ushort4 u;
      u.x = __builtin_bit_cast(unsigned short, (bf16_t)(acc[db][rr * 4 + 0] * inv));
      u.y = __builtin_bit_cast(unsigned short, (bf16_t)(acc[db][rr * 4 + 1] * inv));
      u.z = __builtin_bit_cast(unsigned short, (bf16_t)(acc[db][rr * 4 + 2] * inv));
      u.w = __builtin_bit_cast(unsigned short, (bf16_t)(acc[db][rr * 4 + 3] * inv));
      *(ushort4*)(O + obase + db * 32 + rr * 8 + lh * 4) = u;
    }
}

// ---------------------------------------------------------------- launch
extern "C" void kernel_launch(void* const* d_in, const int* in_sizes, int n_in,
                              void* d_out, int out_size, void* d_ws, size_t ws_size,
                              hipStream_t stream) {
  const float* words     = (const float*)d_in[0];
  const float* position  = (const float*)d_in[1];
  const float* conscious = (const float*)d_in[2];
  const float* w_wq  = (const float*)d_in[3];
  const float* w_wk  = (const float*)d_in[4];
  const float* w_wv  = (const float*)d_in[5];
  const float* w_pq  = (const float*)d_in[6];
  const float* w_pk  = (const float*)d_in[7];
  const float* w_cq  = (const float*)d_in[8];
  const float* w_ck  = (const float*)d_in[9];
  const float* w_out = (const float*)d_in[10];
  const float* b_out = (const float*)d_in[11];

  char* ws = (char*)d_ws;
  bf16_t* Xcat = (bf16_t*)(ws);                 // 48 MiB [8192][3072]
  bf16_t* Wqkt = (bf16_t*)(ws + 50331648);      // 12 MiB [2048][3072]
  bf16_t* Wvt  = (bf16_t*)(ws + 62914560);      // 2 MiB  [1024][1024]
  bf16_t* Wot  = (bf16_t*)(ws + 65011712);      // 2 MiB  [1024][1024]
  bf16_t* Qb   = (bf16_t*)(ws + 67108864);      // 16 MiB [B,H,N,D]
  bf16_t* Kbf  = (bf16_t*)(ws + 83886080);      // 16 MiB [B,H,N,D]
  bf16_t* Vtb  = (bf16_t*)(ws + 100663296);     // 16 MiB [B,H,D,N]
  bf16_t* Ob   = (bf16_t*)(ws + 117440512);     // 16 MiB [B,N,H*D]

  cast_concat<<<24576, 256, 0, stream>>>(words, position, conscious, Xcat);

  transpose_all<<<dim3(32, 32, 8), dim3(32, 8), 0, stream>>>(
      w_wq, w_pq, w_cq, w_wk, w_pk, w_ck, w_wv, w_out, Wqkt, Wvt, Wot);

  // merged Q|K GEMM: 256x256 tiles, 32x8 = 256 blocks (1/CU, no tail)
  gemm256_qk<<<256, 512, 0, stream>>>(Xcat, 3072, Wqkt, 3072, Qb, Kbf,
                                      0.125f * 1.44269504f, 8);
  // V GEMM: 128x256 tiles, 64x4 = 256 blocks (words slice of Xcat, K=1024)
  gemm128x256<1><<<256, 512, 0, stream>>>(Xcat, 3072, Wvt, 1024, Vtb, nullptr);

  attn_kernel<<<512, 512, 0, stream>>>(Qb, Kbf, Vtb, Ob);

  // out GEMM: 128x256 tiles, f32 + bias
  gemm128x256<2><<<256, 512, 0, stream>>>(Ob, 1024, Wot, 1024, (float*)d_out, b_out);
}